// Round 1
// baseline (18065.010 us; speedup 1.0000x reference)
//
#include <hip/hip_runtime.h>

// Problem constants (fixed by the reference setup):
//   E = 800000 edges, D = 64, N = 50000 nodes, MLP 320 -> 256 -> 256 -> 64.
// d_ws layout: agg_sum [N*64] f32, then agg_mul [N*64] f32 (25.6 MB total).

#define TE 32          // edges per block in the fused MLP kernel
#define NNODES 50000

// ---------------------------------------------------------------- atomic mul
__device__ inline void atomicMulF(float* addr, float val) {
    unsigned int* ua = (unsigned int*)addr;
    unsigned int old = *ua, assumed;
    do {
        assumed = old;
        float nv = __uint_as_float(assumed) * val;
        old = atomicCAS(ua, assumed, __float_as_uint(nv));
    } while (old != assumed);
}

// ---------------------------------------------------------------- init agg
__global__ __launch_bounds__(256) void init_agg(float4* __restrict__ aggs,
                                                float4* __restrict__ aggm,
                                                int n4) {
    int t = blockIdx.x * blockDim.x + threadIdx.x;
    if (t < n4) {
        aggs[t] = make_float4(0.f, 0.f, 0.f, 0.f);
        aggm[t] = make_float4(1.f, 1.f, 1.f, 1.f);
    }
}

// ---------------------------------------------------------------- scatter
// one thread per (edge, 4-dim group): 16 threads/edge
__global__ __launch_bounds__(256) void scatter_agg(
    const float4* __restrict__ feat4, const int* __restrict__ ei,
    float* __restrict__ aggs, float* __restrict__ aggm, int E) {
    int t = blockIdx.x * blockDim.x + threadIdx.x;
    if (t >= E * 16) return;
    int e = t >> 4, q = t & 15;
    float4 f = feat4[(size_t)e * 16 + q];
    int u = ei[e], v = ei[E + e];
    size_t bu = (size_t)u * 64 + q * 4;
    size_t bv = (size_t)v * 64 + q * 4;
    atomicAdd(&aggs[bu + 0], f.x); atomicAdd(&aggs[bu + 1], f.y);
    atomicAdd(&aggs[bu + 2], f.z); atomicAdd(&aggs[bu + 3], f.w);
    atomicAdd(&aggs[bv + 0], f.x); atomicAdd(&aggs[bv + 1], f.y);
    atomicAdd(&aggs[bv + 2], f.z); atomicAdd(&aggs[bv + 3], f.w);
    atomicMulF(&aggm[bu + 0], f.x); atomicMulF(&aggm[bu + 1], f.y);
    atomicMulF(&aggm[bu + 2], f.z); atomicMulF(&aggm[bu + 3], f.w);
    atomicMulF(&aggm[bv + 0], f.x); atomicMulF(&aggm[bv + 1], f.y);
    atomicMulF(&aggm[bv + 2], f.z); atomicMulF(&aggm[bv + 3], f.w);
}

// ---------------------------------------------------------------- fused MLP
// block = 256 threads, TE=32 edges. Single LDS buffer reused h0 -> h1 -> h2.
// thread micro-tile: 4 edges (eg = tid>>5) x 8 outputs (o = og + 32*j).
__global__ __launch_bounds__(256) void mlp_fused(
    const float* __restrict__ feat, const int* __restrict__ ei,
    const float* __restrict__ aggs, const float* __restrict__ aggm,
    const float* __restrict__ W1, const float* __restrict__ b1,
    const float* __restrict__ W2, const float* __restrict__ b2,
    const float* __restrict__ W3, const float* __restrict__ b3,
    float* __restrict__ out, int E) {
    __shared__ float buf[TE * 320];   // 40 KB, reused as [TE][320] then [TE][256]
    __shared__ int uv[2][TE];

    const int tid = threadIdx.x;
    const int e0 = blockIdx.x * TE;

    if (tid < 2 * TE) {
        int w = tid / TE, r = tid % TE;
        int e = e0 + r;
        uv[w][r] = (e < E) ? ei[w * E + e] : 0;
    }
    __syncthreads();

    // gather h0 = [feat | sum_u - feat | sum_v - feat | mul_u | mul_v]
    for (int idx = tid; idx < TE * 80; idx += 256) {
        int r = idx / 80;
        int rem = idx % 80;
        int sec = rem >> 4;
        int q = rem & 15;
        int e = e0 + r; if (e >= E) e = E - 1;
        const float4* f4 = (const float4*)(feat + (size_t)e * 64);
        float4 val;
        if (sec == 0) {
            val = f4[q];
        } else if (sec == 1) {
            float4 s = ((const float4*)(aggs + (size_t)uv[0][r] * 64))[q];
            float4 f = f4[q];
            val = make_float4(s.x - f.x, s.y - f.y, s.z - f.z, s.w - f.w);
        } else if (sec == 2) {
            float4 s = ((const float4*)(aggs + (size_t)uv[1][r] * 64))[q];
            float4 f = f4[q];
            val = make_float4(s.x - f.x, s.y - f.y, s.z - f.z, s.w - f.w);
        } else if (sec == 3) {
            val = ((const float4*)(aggm + (size_t)uv[0][r] * 64))[q];
        } else {
            val = ((const float4*)(aggm + (size_t)uv[1][r] * 64))[q];
        }
        *(float4*)&buf[r * 320 + sec * 64 + q * 4] = val;
    }
    __syncthreads();

    const int og = tid & 31;
    const int eg = tid >> 5;

    // ---- layer 1: 320 -> 256, relu
    float acc1[4][8];
    #pragma unroll
    for (int i = 0; i < 4; ++i)
        #pragma unroll
        for (int j = 0; j < 8; ++j) acc1[i][j] = 0.f;

    for (int k = 0; k < 320; k += 4) {
        float4 a[4];
        #pragma unroll
        for (int i = 0; i < 4; ++i) a[i] = *(const float4*)&buf[(eg * 4 + i) * 320 + k];
        #pragma unroll
        for (int j = 0; j < 8; ++j) {
            const float4 w = *(const float4*)&W1[(size_t)(og + 32 * j) * 320 + k];
            #pragma unroll
            for (int i = 0; i < 4; ++i)
                acc1[i][j] += a[i].x * w.x + a[i].y * w.y + a[i].z * w.z + a[i].w * w.w;
        }
    }
    __syncthreads();   // everyone done reading h0
    #pragma unroll
    for (int j = 0; j < 8; ++j) {
        float bj = b1[og + 32 * j];
        #pragma unroll
        for (int i = 0; i < 4; ++i) {
            float v = acc1[i][j] + bj;
            buf[(eg * 4 + i) * 256 + og + 32 * j] = v > 0.f ? v : 0.f;
        }
    }
    __syncthreads();

    // ---- layer 2: 256 -> 256, relu
    float acc2[4][8];
    #pragma unroll
    for (int i = 0; i < 4; ++i)
        #pragma unroll
        for (int j = 0; j < 8; ++j) acc2[i][j] = 0.f;

    for (int k = 0; k < 256; k += 4) {
        float4 a[4];
        #pragma unroll
        for (int i = 0; i < 4; ++i) a[i] = *(const float4*)&buf[(eg * 4 + i) * 256 + k];
        #pragma unroll
        for (int j = 0; j < 8; ++j) {
            const float4 w = *(const float4*)&W2[(size_t)(og + 32 * j) * 256 + k];
            #pragma unroll
            for (int i = 0; i < 4; ++i)
                acc2[i][j] += a[i].x * w.x + a[i].y * w.y + a[i].z * w.z + a[i].w * w.w;
        }
    }
    __syncthreads();
    #pragma unroll
    for (int j = 0; j < 8; ++j) {
        float bj = b2[og + 32 * j];
        #pragma unroll
        for (int i = 0; i < 4; ++i) {
            float v = acc2[i][j] + bj;
            buf[(eg * 4 + i) * 256 + og + 32 * j] = v > 0.f ? v : 0.f;
        }
    }
    __syncthreads();

    // ---- layer 3: 256 -> 64
    float acc3[4][2];
    #pragma unroll
    for (int i = 0; i < 4; ++i) { acc3[i][0] = 0.f; acc3[i][1] = 0.f; }

    for (int k = 0; k < 256; k += 4) {
        float4 a[4];
        #pragma unroll
        for (int i = 0; i < 4; ++i) a[i] = *(const float4*)&buf[(eg * 4 + i) * 256 + k];
        #pragma unroll
        for (int j = 0; j < 2; ++j) {
            const float4 w = *(const float4*)&W3[(size_t)(og + 32 * j) * 256 + k];
            #pragma unroll
            for (int i = 0; i < 4; ++i)
                acc3[i][j] += a[i].x * w.x + a[i].y * w.y + a[i].z * w.z + a[i].w * w.w;
        }
    }
    float b3v0 = b3[og], b3v1 = b3[og + 32];
    #pragma unroll
    for (int i = 0; i < 4; ++i) {
        int e = e0 + eg * 4 + i;
        if (e < E) {
            out[(size_t)e * 64 + og]      = acc3[i][0] + b3v0;
            out[(size_t)e * 64 + og + 32] = acc3[i][1] + b3v1;
        }
    }
}

// ---------------------------------------------------------------- launcher
extern "C" void kernel_launch(void* const* d_in, const int* in_sizes, int n_in,
                              void* d_out, int out_size, void* d_ws, size_t ws_size,
                              hipStream_t stream) {
    const float* feat = (const float*)d_in[0];
    const int*   ei   = (const int*)d_in[1];
    // d_in[2] = num_nodes scalar on device; N fixed by problem spec
    const float* W1 = (const float*)d_in[3];
    const float* b1 = (const float*)d_in[4];
    const float* W2 = (const float*)d_in[5];
    const float* b2 = (const float*)d_in[6];
    const float* W3 = (const float*)d_in[7];
    const float* b3 = (const float*)d_in[8];
    float* out = (float*)d_out;

    const int E = in_sizes[0] / 64;
    const int N = NNODES;

    float* aggs = (float*)d_ws;
    float* aggm = aggs + (size_t)N * 64;

    int n4 = N * 64 / 4;
    hipLaunchKernelGGL(init_agg, dim3((n4 + 255) / 256), dim3(256), 0, stream,
                       (float4*)aggs, (float4*)aggm, n4);

    int nthr = E * 16;
    hipLaunchKernelGGL(scatter_agg, dim3((nthr + 255) / 256), dim3(256), 0, stream,
                       (const float4*)feat, ei, aggs, aggm, E);

    hipLaunchKernelGGL(mlp_fused, dim3((E + TE - 1) / TE), dim3(256), 0, stream,
                       feat, ei, aggs, aggm, W1, b1, W2, b2, W3, b3, out, E);
}

// Round 2
// 6030.630 us; speedup vs baseline: 2.9955x; 2.9955x over previous
//
#include <hip/hip_runtime.h>

// E = 800000, D = 64, N = 50000, MLP 320 -> 256 -> 256 -> 64.
// Strategy: scatter-atomic aggregation (unchanged), then split-bf16 (hi+lo)
// emulated-fp32 MFMA MLP: C = Ah*Bh + Ah*Bl + Al*Bh accumulated in fp32.
//
// d_ws layout: aggs f32[N*64] | aggm f32[N*64] | Wh1,Wl1 u16[81920] |
//              Wh2,Wl2 u16[65536] | Wh3,Wl3 u16[16384]   (~26.3 MB)

#define NNODES 50000
#define MT 32            // edges per MLP block
#define LDK 328          // padded LDS row stride (ushorts)

typedef unsigned short u16;
typedef __attribute__((ext_vector_type(8))) short bf16x8;
typedef __attribute__((ext_vector_type(4))) float f32x4;

// ---------------------------------------------------------------- helpers
__device__ inline void split_bf16(float x, u16& hi, u16& lo) {
    unsigned u = __float_as_uint(x);
    unsigned r = (u + 0x7FFFu + ((u >> 16) & 1u)) >> 16;     // RNE to bf16
    hi = (u16)r;
    float hf = __uint_as_float(r << 16);
    float l = x - hf;                                        // exact
    unsigned ul = __float_as_uint(l);
    unsigned rl = (ul + 0x7FFFu + ((ul >> 16) & 1u)) >> 16;
    lo = (u16)rl;
}

__device__ inline void atomicMulF(float* addr, float val) {
    unsigned int* ua = (unsigned int*)addr;
    unsigned int old = *ua, assumed;
    do {
        assumed = old;
        float nv = __uint_as_float(assumed) * val;
        old = atomicCAS(ua, assumed, __float_as_uint(nv));
    } while (old != assumed);
}

// ---------------------------------------------------------------- init agg
__global__ __launch_bounds__(256) void init_agg(float4* __restrict__ aggs,
                                                float4* __restrict__ aggm,
                                                int n4) {
    int t = blockIdx.x * blockDim.x + threadIdx.x;
    if (t < n4) {
        aggs[t] = make_float4(0.f, 0.f, 0.f, 0.f);
        aggm[t] = make_float4(1.f, 1.f, 1.f, 1.f);
    }
}

// ---------------------------------------------------------------- W split
__global__ __launch_bounds__(256) void split_weights(
    const float* __restrict__ W1, const float* __restrict__ W2,
    const float* __restrict__ W3,
    u16* __restrict__ Wh1, u16* __restrict__ Wl1,
    u16* __restrict__ Wh2, u16* __restrict__ Wl2,
    u16* __restrict__ Wh3, u16* __restrict__ Wl3) {
    int t = blockIdx.x * blockDim.x + threadIdx.x;
    u16 h, l;
    if (t < 81920) {
        split_bf16(W1[t], h, l); Wh1[t] = h; Wl1[t] = l;
    } else if (t < 81920 + 65536) {
        int i = t - 81920;
        split_bf16(W2[i], h, l); Wh2[i] = h; Wl2[i] = l;
    } else if (t < 163840) {
        int i = t - 147456;
        split_bf16(W3[i], h, l); Wh3[i] = h; Wl3[i] = l;
    }
}

// ---------------------------------------------------------------- scatter
__global__ __launch_bounds__(256) void scatter_agg(
    const float4* __restrict__ feat4, const int* __restrict__ ei,
    float* __restrict__ aggs, float* __restrict__ aggm, int E) {
    int t = blockIdx.x * blockDim.x + threadIdx.x;
    if (t >= E * 16) return;
    int e = t >> 4, q = t & 15;
    float4 f = feat4[(size_t)e * 16 + q];
    int u = ei[e], v = ei[E + e];
    size_t bu = (size_t)u * 64 + q * 4;
    size_t bv = (size_t)v * 64 + q * 4;
    atomicAdd(&aggs[bu + 0], f.x); atomicAdd(&aggs[bu + 1], f.y);
    atomicAdd(&aggs[bu + 2], f.z); atomicAdd(&aggs[bu + 3], f.w);
    atomicAdd(&aggs[bv + 0], f.x); atomicAdd(&aggs[bv + 1], f.y);
    atomicAdd(&aggs[bv + 2], f.z); atomicAdd(&aggs[bv + 3], f.w);
    atomicMulF(&aggm[bu + 0], f.x); atomicMulF(&aggm[bu + 1], f.y);
    atomicMulF(&aggm[bu + 2], f.z); atomicMulF(&aggm[bu + 3], f.w);
    atomicMulF(&aggm[bv + 0], f.x); atomicMulF(&aggm[bv + 1], f.y);
    atomicMulF(&aggm[bv + 2], f.z); atomicMulF(&aggm[bv + 3], f.w);
}

// ---------------------------------------------------------------- MFMA MLP
// 256 threads = 4 waves, 32 edges/block. Wave w owns output cols [w*64, w*64+64)
// for layers 1/2 and cols [w*16, w*16+16) for layer 3.
// Fragment layout (gemm_bt-verified): A/B lane&15 = row, k = (lane>>4)*8 + i.
// D: col = lane&15, row = (lane>>4)*4 + reg.
__global__ __launch_bounds__(256, 3) void mlp_mfma(
    const float* __restrict__ feat, const int* __restrict__ ei,
    const float* __restrict__ aggs, const float* __restrict__ aggm,
    const u16* __restrict__ Wh1, const u16* __restrict__ Wl1,
    const u16* __restrict__ Wh2, const u16* __restrict__ Wl2,
    const u16* __restrict__ Wh3, const u16* __restrict__ Wl3,
    const float* __restrict__ b1, const float* __restrict__ b2,
    const float* __restrict__ b3,
    float* __restrict__ out, int E) {
    __shared__ u16 Ah[MT][LDK];
    __shared__ u16 Al[MT][LDK];
    __shared__ int uv[2][MT];

    const int tid = threadIdx.x;
    const int e0 = blockIdx.x * MT;

    if (tid < 2 * MT) {
        int w = tid >> 5, r = tid & 31;
        int e = e0 + r;
        uv[w][r] = (e < E) ? ei[w * E + e] : 0;
    }
    __syncthreads();

    // ---- gather h0 = [feat | sum_u - f | sum_v - f | mul_u | mul_v] -> bf16 hi/lo
    for (int idx = tid; idx < MT * 80; idx += 256) {
        int r = idx / 80, rem = idx % 80;
        int sec = rem >> 4, q = rem & 15;
        int e = e0 + r; if (e >= E) e = E - 1;
        const float4* f4 = (const float4*)(feat + (size_t)e * 64);
        float4 val;
        if (sec == 0) {
            val = f4[q];
        } else if (sec == 1) {
            float4 s = ((const float4*)(aggs + (size_t)uv[0][r] * 64))[q];
            float4 f = f4[q];
            val = make_float4(s.x - f.x, s.y - f.y, s.z - f.z, s.w - f.w);
        } else if (sec == 2) {
            float4 s = ((const float4*)(aggs + (size_t)uv[1][r] * 64))[q];
            float4 f = f4[q];
            val = make_float4(s.x - f.x, s.y - f.y, s.z - f.z, s.w - f.w);
        } else if (sec == 3) {
            val = ((const float4*)(aggm + (size_t)uv[0][r] * 64))[q];
        } else {
            val = ((const float4*)(aggm + (size_t)uv[1][r] * 64))[q];
        }
        u16 h0, h1, h2, h3, l0, l1, l2, l3;
        split_bf16(val.x, h0, l0); split_bf16(val.y, h1, l1);
        split_bf16(val.z, h2, l2); split_bf16(val.w, h3, l3);
        int col = sec * 64 + q * 4;
        *(ushort4*)&Ah[r][col] = make_ushort4(h0, h1, h2, h3);
        *(ushort4*)&Al[r][col] = make_ushort4(l0, l1, l2, l3);
    }
    __syncthreads();

    const int lane = tid & 63;
    const int w = tid >> 6;
    const int lrow = lane & 15;
    const int kgrp = (lane >> 4) * 8;

    f32x4 acc[2][4];
    const f32x4 zf = {0.f, 0.f, 0.f, 0.f};

    // ================= layer 1: K=320, N-slice = w*64..w*64+63, relu
    #pragma unroll
    for (int t = 0; t < 2; ++t)
        #pragma unroll
        for (int j = 0; j < 4; ++j) acc[t][j] = zf;
    {
        size_t wb[4];
        #pragma unroll
        for (int j = 0; j < 4; ++j)
            wb[j] = (size_t)(w * 64 + j * 16 + lrow) * 320 + kgrp;
        for (int kk = 0; kk < 320; kk += 32) {
            bf16x8 ah[2], al[2];
            #pragma unroll
            for (int t = 0; t < 2; ++t) {
                ah[t] = *(const bf16x8*)&Ah[t * 16 + lrow][kk + kgrp];
                al[t] = *(const bf16x8*)&Al[t * 16 + lrow][kk + kgrp];
            }
            #pragma unroll
            for (int j = 0; j < 4; ++j) {
                bf16x8 bh = *(const bf16x8*)&Wh1[wb[j] + kk];
                bf16x8 bl = *(const bf16x8*)&Wl1[wb[j] + kk];
                #pragma unroll
                for (int t = 0; t < 2; ++t) {
                    acc[t][j] = __builtin_amdgcn_mfma_f32_16x16x32_bf16(ah[t], bh, acc[t][j], 0, 0, 0);
                    acc[t][j] = __builtin_amdgcn_mfma_f32_16x16x32_bf16(ah[t], bl, acc[t][j], 0, 0, 0);
                    acc[t][j] = __builtin_amdgcn_mfma_f32_16x16x32_bf16(al[t], bh, acc[t][j], 0, 0, 0);
                }
            }
        }
    }
    __syncthreads();
    #pragma unroll
    for (int t = 0; t < 2; ++t)
        #pragma unroll
        for (int j = 0; j < 4; ++j) {
            int n = w * 64 + j * 16 + lrow;
            float bj = b1[n];
            #pragma unroll
            for (int r = 0; r < 4; ++r) {
                int m = t * 16 + (lane >> 4) * 4 + r;
                float v = acc[t][j][r] + bj;
                v = v > 0.f ? v : 0.f;
                u16 h, l;
                split_bf16(v, h, l);
                Ah[m][n] = h; Al[m][n] = l;
            }
        }
    __syncthreads();

    // ================= layer 2: K=256, relu
    #pragma unroll
    for (int t = 0; t < 2; ++t)
        #pragma unroll
        for (int j = 0; j < 4; ++j) acc[t][j] = zf;
    {
        size_t wb[4];
        #pragma unroll
        for (int j = 0; j < 4; ++j)
            wb[j] = (size_t)(w * 64 + j * 16 + lrow) * 256 + kgrp;
        for (int kk = 0; kk < 256; kk += 32) {
            bf16x8 ah[2], al[2];
            #pragma unroll
            for (int t = 0; t < 2; ++t) {
                ah[t] = *(const bf16x8*)&Ah[t * 16 + lrow][kk + kgrp];
                al[t] = *(const bf16x8*)&Al[t * 16 + lrow][kk + kgrp];
            }
            #pragma unroll
            for (int j = 0; j < 4; ++j) {
                bf16x8 bh = *(const bf16x8*)&Wh2[wb[j] + kk];
                bf16x8 bl = *(const bf16x8*)&Wl2[wb[j] + kk];
                #pragma unroll
                for (int t = 0; t < 2; ++t) {
                    acc[t][j] = __builtin_amdgcn_mfma_f32_16x16x32_bf16(ah[t], bh, acc[t][j], 0, 0, 0);
                    acc[t][j] = __builtin_amdgcn_mfma_f32_16x16x32_bf16(ah[t], bl, acc[t][j], 0, 0, 0);
                    acc[t][j] = __builtin_amdgcn_mfma_f32_16x16x32_bf16(al[t], bh, acc[t][j], 0, 0, 0);
                }
            }
        }
    }
    __syncthreads();
    #pragma unroll
    for (int t = 0; t < 2; ++t)
        #pragma unroll
        for (int j = 0; j < 4; ++j) {
            int n = w * 64 + j * 16 + lrow;
            float bj = b2[n];
            #pragma unroll
            for (int r = 0; r < 4; ++r) {
                int m = t * 16 + (lane >> 4) * 4 + r;
                float v = acc[t][j][r] + bj;
                v = v > 0.f ? v : 0.f;
                u16 h, l;
                split_bf16(v, h, l);
                Ah[m][n] = h; Al[m][n] = l;
            }
        }
    __syncthreads();

    // ================= layer 3: K=256, N=64 (wave w -> cols w*16..w*16+15)
    f32x4 acc3[2];
    acc3[0] = zf; acc3[1] = zf;
    {
        size_t wb = (size_t)(w * 16 + lrow) * 256 + kgrp;
        for (int kk = 0; kk < 256; kk += 32) {
            bf16x8 ah[2], al[2];
            #pragma unroll
            for (int t = 0; t < 2; ++t) {
                ah[t] = *(const bf16x8*)&Ah[t * 16 + lrow][kk + kgrp];
                al[t] = *(const bf16x8*)&Al[t * 16 + lrow][kk + kgrp];
            }
            bf16x8 bh = *(const bf16x8*)&Wh3[wb + kk];
            bf16x8 bl = *(const bf16x8*)&Wl3[wb + kk];
            #pragma unroll
            for (int t = 0; t < 2; ++t) {
                acc3[t] = __builtin_amdgcn_mfma_f32_16x16x32_bf16(ah[t], bh, acc3[t], 0, 0, 0);
                acc3[t] = __builtin_amdgcn_mfma_f32_16x16x32_bf16(ah[t], bl, acc3[t], 0, 0, 0);
                acc3[t] = __builtin_amdgcn_mfma_f32_16x16x32_bf16(al[t], bh, acc3[t], 0, 0, 0);
            }
        }
    }
    {
        int n = w * 16 + lrow;
        float bj = b3[n];
        #pragma unroll
        for (int t = 0; t < 2; ++t)
            #pragma unroll
            for (int r = 0; r < 4; ++r) {
                int m = t * 16 + (lane >> 4) * 4 + r;
                int e = e0 + m;
                if (e < E) out[(size_t)e * 64 + n] = acc3[t][r] + bj;
            }
    }
}

// ---------------------------------------------------------------- launcher
extern "C" void kernel_launch(void* const* d_in, const int* in_sizes, int n_in,
                              void* d_out, int out_size, void* d_ws, size_t ws_size,
                              hipStream_t stream) {
    const float* feat = (const float*)d_in[0];
    const int*   ei   = (const int*)d_in[1];
    const float* W1 = (const float*)d_in[3];
    const float* b1 = (const float*)d_in[4];
    const float* W2 = (const float*)d_in[5];
    const float* b2 = (const float*)d_in[6];
    const float* W3 = (const float*)d_in[7];
    const float* b3 = (const float*)d_in[8];
    float* out = (float*)d_out;

    const int E = in_sizes[0] / 64;
    const int N = NNODES;

    float* aggs = (float*)d_ws;
    float* aggm = aggs + (size_t)N * 64;
    u16* Wh1 = (u16*)(aggm + (size_t)N * 64);
    u16* Wl1 = Wh1 + 81920;
    u16* Wh2 = Wl1 + 81920;
    u16* Wl2 = Wh2 + 65536;
    u16* Wh3 = Wl2 + 65536;
    u16* Wl3 = Wh3 + 16384;

    int n4 = N * 64 / 4;
    hipLaunchKernelGGL(init_agg, dim3((n4 + 255) / 256), dim3(256), 0, stream,
                       (float4*)aggs, (float4*)aggm, n4);

    hipLaunchKernelGGL(split_weights, dim3(640), dim3(256), 0, stream,
                       W1, W2, W3, Wh1, Wl1, Wh2, Wl2, Wh3, Wl3);

    int nthr = E * 16;
    hipLaunchKernelGGL(scatter_agg, dim3((nthr + 255) / 256), dim3(256), 0, stream,
                       (const float4*)feat, ei, aggs, aggm, E);

    hipLaunchKernelGGL(mlp_mfma, dim3((E + MT - 1) / MT), dim3(256), 0, stream,
                       feat, ei, aggs, aggm,
                       Wh1, Wl1, Wh2, Wl2, Wh3, Wl3,
                       b1, b2, b3, out, E);
}

// Round 3
// 2114.455 us; speedup vs baseline: 8.5436x; 2.8521x over previous
//
#include <hip/hip_runtime.h>

// E = 800000, D = 64, N = 50000, MLP 320 -> 256 -> 256 -> 64.
// R2: CSR-based aggregation (no float atomics) + split-bf16 MFMA MLP with
// fragment-packed weights (coalesced B loads) and M=96 edge tiles.
//
// d_ws: aggs f32[N*64] | aggm f32[N*64] | P1h/P1l u16[81920] | P2h/P2l u16[65536]
//       | P3h/P3l u16[16384] | deg int[N] | cursor int[N] | off int[N+16] | elist int[2E]

#define NNODES 50000
#define MT 96            // edges per MLP block
#define LDK 328          // padded LDS row stride (u16)

typedef unsigned short u16;
typedef __attribute__((ext_vector_type(8))) short bf16x8;
typedef __attribute__((ext_vector_type(4))) float f32x4;

__device__ inline void split_bf16(float x, u16& hi, u16& lo) {
    unsigned u = __float_as_uint(x);
    unsigned r = (u + 0x7FFFu + ((u >> 16) & 1u)) >> 16;     // RNE to bf16
    hi = (u16)r;
    float hf = __uint_as_float(r << 16);
    float l = x - hf;                                        // exact residual
    unsigned ul = __float_as_uint(l);
    unsigned rl = (ul + 0x7FFFu + ((ul >> 16) & 1u)) >> 16;
    lo = (u16)rl;
}

// ---------------------------------------------------------------- CSR build
__global__ __launch_bounds__(256) void csr_init(int* __restrict__ deg,
                                                int* __restrict__ cursor, int n) {
    int t = blockIdx.x * 256 + threadIdx.x;
    if (t < n) { deg[t] = 0; cursor[t] = 0; }
}

__global__ __launch_bounds__(256) void count_deg(const int* __restrict__ ei,
                                                 int* __restrict__ deg, int twoE) {
    int t = blockIdx.x * 256 + threadIdx.x;
    if (t < twoE) atomicAdd(&deg[ei[t]], 1);
}

__global__ __launch_bounds__(1024) void scan_deg(const int* __restrict__ deg,
                                                 int* __restrict__ off, int n) {
    __shared__ int buf[1024];
    __shared__ int carry;
    int tid = threadIdx.x;
    if (tid == 0) carry = 0;
    __syncthreads();
    for (int base = 0; base < n; base += 1024) {
        int v = (base + tid < n) ? deg[base + tid] : 0;
        buf[tid] = v;
        __syncthreads();
        int acc = v;
        for (int s = 1; s < 1024; s <<= 1) {
            int t = (tid >= s) ? buf[tid - s] : 0;
            __syncthreads();
            acc += t;
            buf[tid] = acc;
            __syncthreads();
        }
        if (base + tid < n) off[base + tid] = carry + acc - v;
        int total = buf[1023];
        __syncthreads();
        if (tid == 0) carry += total;
        __syncthreads();
    }
    if (tid == 0) off[n] = carry;
}

__global__ __launch_bounds__(256) void fill_csr(const int* __restrict__ ei,
                                                const int* __restrict__ off,
                                                int* __restrict__ cursor,
                                                int* __restrict__ elist,
                                                int E) {
    int t = blockIdx.x * 256 + threadIdx.x;
    if (t >= 2 * E) return;
    int n = ei[t];
    int p = atomicAdd(&cursor[n], 1);
    elist[off[n] + p] = (t < E) ? t : t - E;
}

// one wave per node; lanes: g = lane>>4 (edge sub-stream), q = lane&15 (dim quad)
__global__ __launch_bounds__(256) void node_aggregate(
    const float4* __restrict__ feat4, const int* __restrict__ off,
    const int* __restrict__ elist,
    float4* __restrict__ aggs4, float4* __restrict__ aggm4, int nNodes) {
    int node = blockIdx.x * 4 + (threadIdx.x >> 6);
    if (node >= nNodes) return;
    int lane = threadIdx.x & 63;
    int g = lane >> 4, q = lane & 15;
    int beg = off[node], end = off[node + 1];
    float4 s = make_float4(0.f, 0.f, 0.f, 0.f);
    float4 p = make_float4(1.f, 1.f, 1.f, 1.f);
    for (int i = beg + g; i < end; i += 4) {
        float4 x = feat4[(size_t)elist[i] * 16 + q];
        s.x += x.x; s.y += x.y; s.z += x.z; s.w += x.w;
        p.x *= x.x; p.y *= x.y; p.z *= x.z; p.w *= x.w;
    }
    #pragma unroll
    for (int d = 16; d < 64; d <<= 1) {
        s.x += __shfl_xor(s.x, d); s.y += __shfl_xor(s.y, d);
        s.z += __shfl_xor(s.z, d); s.w += __shfl_xor(s.w, d);
        p.x *= __shfl_xor(p.x, d); p.y *= __shfl_xor(p.y, d);
        p.z *= __shfl_xor(p.z, d); p.w *= __shfl_xor(p.w, d);
    }
    if (g == 0) {
        aggs4[(size_t)node * 16 + q] = s;
        aggm4[(size_t)node * 16 + q] = p;
    }
}

// ---------------------------------------------------------------- W pack
// Fragment layout: frag = (ct*KT + kt)*64 + lane; lane holds
// W[ct*16 + (lane&15)][kt*32 + (lane>>4)*8 + j], j=0..7, split into hi/lo bf16.
__global__ __launch_bounds__(256) void pack_weights(
    const float* __restrict__ W1, const float* __restrict__ W2,
    const float* __restrict__ W3,
    u16* __restrict__ P1h, u16* __restrict__ P1l,
    u16* __restrict__ P2h, u16* __restrict__ P2l,
    u16* __restrict__ P3h, u16* __restrict__ P3l) {
    int t = blockIdx.x * 256 + threadIdx.x;
    const float* W; u16 *Ph, *Pl; int K, frag;
    if (t < 10240)        { W = W1; Ph = P1h; Pl = P1l; K = 320; frag = t; }
    else if (t < 18432)   { W = W2; Ph = P2h; Pl = P2l; K = 256; frag = t - 10240; }
    else if (t < 20480)   { W = W3; Ph = P3h; Pl = P3l; K = 256; frag = t - 18432; }
    else return;
    int KT = K / 32;
    int lane = frag & 63;
    int tile = frag >> 6;
    int kt = tile % KT;
    int ct = tile / KT;
    int row = ct * 16 + (lane & 15);
    int k0 = kt * 32 + (lane >> 4) * 8;
    const float* src = W + (size_t)row * K + k0;
    u16* dh = Ph + (size_t)frag * 8;
    u16* dl = Pl + (size_t)frag * 8;
    #pragma unroll
    for (int j = 0; j < 8; ++j) {
        u16 h, l;
        split_bf16(src[j], h, l);
        dh[j] = h; dl[j] = l;
    }
}

// ---------------------------------------------------------------- MFMA MLP
// 512 threads = 8 waves (2 row-groups x 4 col-groups), MT=96 edges (6 row-tiles).
// A/B frag: lane&15 = row, k = (lane>>4)*8 + i. D: col = lane&15, row = (lane>>4)*4 + reg.
__global__ __launch_bounds__(512, 1) void mlp_mfma(
    const float* __restrict__ feat, const int* __restrict__ ei,
    const float* __restrict__ aggs, const float* __restrict__ aggm,
    const u16* __restrict__ P1h, const u16* __restrict__ P1l,
    const u16* __restrict__ P2h, const u16* __restrict__ P2l,
    const u16* __restrict__ P3h, const u16* __restrict__ P3l,
    const float* __restrict__ b1, const float* __restrict__ b2,
    const float* __restrict__ b3,
    float* __restrict__ out, int E) {
    __shared__ u16 Ah[MT][LDK];
    __shared__ u16 Al[MT][LDK];
    __shared__ int uv[2][MT];

    const int tid = threadIdx.x;
    const int e0 = blockIdx.x * MT;

    if (tid < 2 * MT) {
        int w = tid / MT, r = tid - w * MT;
        int e = e0 + r;
        uv[w][r] = (e < E) ? ei[w * E + e] : 0;
    }
    __syncthreads();

    // gather h0 = [feat | sum_u - f | sum_v - f | mul_u | mul_v] -> bf16 hi/lo
    for (int idx = tid; idx < MT * 80; idx += 512) {
        int r = idx / 80, rem = idx - r * 80;
        int sec = rem >> 4, q = rem & 15;
        int e = e0 + r; if (e >= E) e = E - 1;
        const float4* f4 = (const float4*)(feat + (size_t)e * 64);
        float4 val;
        if (sec == 0) {
            val = f4[q];
        } else if (sec == 1) {
            float4 s = ((const float4*)(aggs + (size_t)uv[0][r] * 64))[q];
            float4 f = f4[q];
            val = make_float4(s.x - f.x, s.y - f.y, s.z - f.z, s.w - f.w);
        } else if (sec == 2) {
            float4 s = ((const float4*)(aggs + (size_t)uv[1][r] * 64))[q];
            float4 f = f4[q];
            val = make_float4(s.x - f.x, s.y - f.y, s.z - f.z, s.w - f.w);
        } else if (sec == 3) {
            val = ((const float4*)(aggm + (size_t)uv[0][r] * 64))[q];
        } else {
            val = ((const float4*)(aggm + (size_t)uv[1][r] * 64))[q];
        }
        u16 h0, h1, h2, h3, l0, l1, l2, l3;
        split_bf16(val.x, h0, l0); split_bf16(val.y, h1, l1);
        split_bf16(val.z, h2, l2); split_bf16(val.w, h3, l3);
        int col = sec * 64 + q * 4;
        *(ushort4*)&Ah[r][col] = make_ushort4(h0, h1, h2, h3);
        *(ushort4*)&Al[r][col] = make_ushort4(l0, l1, l2, l3);
    }
    __syncthreads();

    const int lane = tid & 63;
    const int w = tid >> 6;
    const int wr = w >> 2;        // 0..1 (row group: rows wr*48 .. wr*48+47)
    const int wc = w & 3;         // 0..3 (col group: cols wc*64 .. wc*64+63)
    const int lrow = lane & 15;
    const int kgrp = (lane >> 4) * 8;

    const f32x4 zf = {0.f, 0.f, 0.f, 0.f};
    f32x4 acc[3][4];

    // ================= layer 1: K=320 (KT=10), relu
    #pragma unroll
    for (int i = 0; i < 3; ++i)
        #pragma unroll
        for (int j = 0; j < 4; ++j) acc[i][j] = zf;
    for (int kt = 0; kt < 10; ++kt) {
        bf16x8 ah[3], al[3];
        #pragma unroll
        for (int i = 0; i < 3; ++i) {
            int m = (wr * 3 + i) * 16 + lrow;
            ah[i] = *(const bf16x8*)&Ah[m][kt * 32 + kgrp];
            al[i] = *(const bf16x8*)&Al[m][kt * 32 + kgrp];
        }
        #pragma unroll
        for (int j = 0; j < 4; ++j) {
            int ct = wc * 4 + j;
            const size_t fb = ((size_t)(ct * 10 + kt) * 64 + lane) * 8;
            bf16x8 bh = *(const bf16x8*)&P1h[fb];
            bf16x8 bl = *(const bf16x8*)&P1l[fb];
            #pragma unroll
            for (int i = 0; i < 3; ++i) {
                acc[i][j] = __builtin_amdgcn_mfma_f32_16x16x32_bf16(ah[i], bh, acc[i][j], 0, 0, 0);
                acc[i][j] = __builtin_amdgcn_mfma_f32_16x16x32_bf16(ah[i], bl, acc[i][j], 0, 0, 0);
                acc[i][j] = __builtin_amdgcn_mfma_f32_16x16x32_bf16(al[i], bh, acc[i][j], 0, 0, 0);
            }
        }
    }
    __syncthreads();
    #pragma unroll
    for (int j = 0; j < 4; ++j) {
        int n = wc * 64 + j * 16 + lrow;
        float bj = b1[n];
        #pragma unroll
        for (int i = 0; i < 3; ++i) {
            int mbase = (wr * 3 + i) * 16 + (lane >> 4) * 4;
            #pragma unroll
            for (int r = 0; r < 4; ++r) {
                float v = acc[i][j][r] + bj;
                v = v > 0.f ? v : 0.f;
                u16 h, l;
                split_bf16(v, h, l);
                Ah[mbase + r][n] = h;
                Al[mbase + r][n] = l;
            }
        }
    }
    __syncthreads();

    // ================= layer 2: K=256 (KT=8), relu
    #pragma unroll
    for (int i = 0; i < 3; ++i)
        #pragma unroll
        for (int j = 0; j < 4; ++j) acc[i][j] = zf;
    for (int kt = 0; kt < 8; ++kt) {
        bf16x8 ah[3], al[3];
        #pragma unroll
        for (int i = 0; i < 3; ++i) {
            int m = (wr * 3 + i) * 16 + lrow;
            ah[i] = *(const bf16x8*)&Ah[m][kt * 32 + kgrp];
            al[i] = *(const bf16x8*)&Al[m][kt * 32 + kgrp];
        }
        #pragma unroll
        for (int j = 0; j < 4; ++j) {
            int ct = wc * 4 + j;
            const size_t fb = ((size_t)(ct * 8 + kt) * 64 + lane) * 8;
            bf16x8 bh = *(const bf16x8*)&P2h[fb];
            bf16x8 bl = *(const bf16x8*)&P2l[fb];
            #pragma unroll
            for (int i = 0; i < 3; ++i) {
                acc[i][j] = __builtin_amdgcn_mfma_f32_16x16x32_bf16(ah[i], bh, acc[i][j], 0, 0, 0);
                acc[i][j] = __builtin_amdgcn_mfma_f32_16x16x32_bf16(ah[i], bl, acc[i][j], 0, 0, 0);
                acc[i][j] = __builtin_amdgcn_mfma_f32_16x16x32_bf16(al[i], bh, acc[i][j], 0, 0, 0);
            }
        }
    }
    __syncthreads();
    #pragma unroll
    for (int j = 0; j < 4; ++j) {
        int n = wc * 64 + j * 16 + lrow;
        float bj = b2[n];
        #pragma unroll
        for (int i = 0; i < 3; ++i) {
            int mbase = (wr * 3 + i) * 16 + (lane >> 4) * 4;
            #pragma unroll
            for (int r = 0; r < 4; ++r) {
                float v = acc[i][j][r] + bj;
                v = v > 0.f ? v : 0.f;
                u16 h, l;
                split_bf16(v, h, l);
                Ah[mbase + r][n] = h;
                Al[mbase + r][n] = l;
            }
        }
    }
    __syncthreads();

    // ================= layer 3: K=256 (KT=8), N=64 (4 col-tiles)
    // 24 (rt,ct) pairs over 8 waves: p = w*3 + q
    f32x4 acc3[3];
    acc3[0] = zf; acc3[1] = zf; acc3[2] = zf;
    for (int kt = 0; kt < 8; ++kt) {
        #pragma unroll
        for (int q = 0; q < 3; ++q) {
            int p = w * 3 + q;
            int rt = p >> 2, ct = p & 3;
            int m = rt * 16 + lrow;
            bf16x8 ah = *(const bf16x8*)&Ah[m][kt * 32 + kgrp];
            bf16x8 al = *(const bf16x8*)&Al[m][kt * 32 + kgrp];
            const size_t fb = ((size_t)(ct * 8 + kt) * 64 + lane) * 8;
            bf16x8 bh = *(const bf16x8*)&P3h[fb];
            bf16x8 bl = *(const bf16x8*)&P3l[fb];
            acc3[q] = __builtin_amdgcn_mfma_f32_16x16x32_bf16(ah, bh, acc3[q], 0, 0, 0);
            acc3[q] = __builtin_amdgcn_mfma_f32_16x16x32_bf16(ah, bl, acc3[q], 0, 0, 0);
            acc3[q] = __builtin_amdgcn_mfma_f32_16x16x32_bf16(al, bh, acc3[q], 0, 0, 0);
        }
    }
    #pragma unroll
    for (int q = 0; q < 3; ++q) {
        int p = w * 3 + q;
        int rt = p >> 2, ct = p & 3;
        int n = ct * 16 + lrow;
        float bj = b3[n];
        #pragma unroll
        for (int r = 0; r < 4; ++r) {
            int m = rt * 16 + (lane >> 4) * 4 + r;
            int e = e0 + m;
            if (e < E) out[(size_t)e * 64 + n] = acc3[q][r] + bj;
        }
    }
}

// ---------------------------------------------------------------- launcher
extern "C" void kernel_launch(void* const* d_in, const int* in_sizes, int n_in,
                              void* d_out, int out_size, void* d_ws, size_t ws_size,
                              hipStream_t stream) {
    const float* feat = (const float*)d_in[0];
    const int*   ei   = (const int*)d_in[1];
    const float* W1 = (const float*)d_in[3];
    const float* b1 = (const float*)d_in[4];
    const float* W2 = (const float*)d_in[5];
    const float* b2 = (const float*)d_in[6];
    const float* W3 = (const float*)d_in[7];
    const float* b3 = (const float*)d_in[8];
    float* out = (float*)d_out;

    const int E = in_sizes[0] / 64;
    const int N = NNODES;

    char* p = (char*)d_ws;
    float* aggs = (float*)p;            p += (size_t)N * 64 * 4;
    float* aggm = (float*)p;            p += (size_t)N * 64 * 4;
    u16* P1h = (u16*)p;                 p += 81920 * 2;
    u16* P1l = (u16*)p;                 p += 81920 * 2;
    u16* P2h = (u16*)p;                 p += 65536 * 2;
    u16* P2l = (u16*)p;                 p += 65536 * 2;
    u16* P3h = (u16*)p;                 p += 16384 * 2;
    u16* P3l = (u16*)p;                 p += 16384 * 2;
    int* deg = (int*)p;                 p += (size_t)N * 4;
    int* cursor = (int*)p;              p += (size_t)N * 4;
    int* off = (int*)p;                 p += (size_t)(N + 16) * 4;
    int* elist = (int*)p;               p += (size_t)2 * E * 4;

    hipLaunchKernelGGL(csr_init, dim3((N + 255) / 256), dim3(256), 0, stream,
                       deg, cursor, N);
    hipLaunchKernelGGL(count_deg, dim3((2 * E + 255) / 256), dim3(256), 0, stream,
                       ei, deg, 2 * E);
    hipLaunchKernelGGL(scan_deg, dim3(1), dim3(1024), 0, stream, deg, off, N);
    hipLaunchKernelGGL(fill_csr, dim3((2 * E + 255) / 256), dim3(256), 0, stream,
                       ei, off, cursor, elist, E);
    hipLaunchKernelGGL(node_aggregate, dim3((N + 3) / 4), dim3(256), 0, stream,
                       (const float4*)feat, off, elist,
                       (float4*)aggs, (float4*)aggm, N);
    hipLaunchKernelGGL(pack_weights, dim3(80), dim3(256), 0, stream,
                       W1, W2, W3, P1h, P1l, P2h, P2l, P3h, P3l);
    hipLaunchKernelGGL(mlp_mfma, dim3((E + MT - 1) / MT), dim3(512), 0, stream,
                       feat, ei, aggs, aggm,
                       P1h, P1l, P2h, P2l, P3h, P3l,
                       b1, b2, b3, out, E);
}

// Round 4
// 1657.448 us; speedup vs baseline: 10.8993x; 1.2757x over previous
//
#include <hip/hip_runtime.h>

// E = 800000, D = 64, N = 50000, MLP 320 -> 256 -> 256 -> 64.
// R3: CSR aggregation + split-bf16 MFMA MLP.
//   - A-tile LDS XOR-swizzled (byte ^= (m&7)<<4): conflict-free ds_read_b128
//   - MT=64, LDS = 80 KiB exactly -> 2 blocks/CU (4 waves/SIMD)
//
// d_ws: aggs f32[N*64] | aggm f32[N*64] | P1h/P1l u16[81920] | P2h/P2l u16[65536]
//       | P3h/P3l u16[16384] | deg int[N] | cursor int[N] | off int[N+16] | elist int[2E]

#define NNODES 50000
#define MT 64            // edges per MLP block

typedef unsigned short u16;
typedef __attribute__((ext_vector_type(8))) short bf16x8;
typedef __attribute__((ext_vector_type(4))) float f32x4;

__device__ inline void split_bf16(float x, u16& hi, u16& lo) {
    unsigned u = __float_as_uint(x);
    unsigned r = (u + 0x7FFFu + ((u >> 16) & 1u)) >> 16;     // RNE to bf16
    hi = (u16)r;
    float hf = __uint_as_float(r << 16);
    float l = x - hf;                                        // exact residual
    unsigned ul = __float_as_uint(l);
    unsigned rl = (ul + 0x7FFFu + ((ul >> 16) & 1u)) >> 16;
    lo = (u16)rl;
}

// swizzled A-tile address: element (m,k) of a [64][320] u16 tile
__device__ __forceinline__ void* a_ptr(u16* base, int m, int k) {
    int byte = (m * 320 + k) * 2;
    byte ^= (m & 7) << 4;
    return (char*)base + byte;
}
__device__ __forceinline__ const void* a_ptr_c(const u16* base, int m, int k) {
    int byte = (m * 320 + k) * 2;
    byte ^= (m & 7) << 4;
    return (const char*)base + byte;
}

// ---------------------------------------------------------------- CSR build
__global__ __launch_bounds__(256) void csr_init(int* __restrict__ deg,
                                                int* __restrict__ cursor, int n) {
    int t = blockIdx.x * 256 + threadIdx.x;
    if (t < n) { deg[t] = 0; cursor[t] = 0; }
}

__global__ __launch_bounds__(256) void count_deg(const int* __restrict__ ei,
                                                 int* __restrict__ deg, int twoE) {
    int t = blockIdx.x * 256 + threadIdx.x;
    if (t < twoE) atomicAdd(&deg[ei[t]], 1);
}

__global__ __launch_bounds__(1024) void scan_deg(const int* __restrict__ deg,
                                                 int* __restrict__ off, int n) {
    __shared__ int buf[1024];
    __shared__ int carry;
    int tid = threadIdx.x;
    if (tid == 0) carry = 0;
    __syncthreads();
    for (int base = 0; base < n; base += 1024) {
        int v = (base + tid < n) ? deg[base + tid] : 0;
        buf[tid] = v;
        __syncthreads();
        int acc = v;
        for (int s = 1; s < 1024; s <<= 1) {
            int t = (tid >= s) ? buf[tid - s] : 0;
            __syncthreads();
            acc += t;
            buf[tid] = acc;
            __syncthreads();
        }
        if (base + tid < n) off[base + tid] = carry + acc - v;
        int total = buf[1023];
        __syncthreads();
        if (tid == 0) carry += total;
        __syncthreads();
    }
    if (tid == 0) off[n] = carry;
}

__global__ __launch_bounds__(256) void fill_csr(const int* __restrict__ ei,
                                                const int* __restrict__ off,
                                                int* __restrict__ cursor,
                                                int* __restrict__ elist,
                                                int E) {
    int t = blockIdx.x * 256 + threadIdx.x;
    if (t >= 2 * E) return;
    int n = ei[t];
    int p = atomicAdd(&cursor[n], 1);
    elist[off[n] + p] = (t < E) ? t : t - E;
}

// one wave per node; lanes: g = lane>>4 (edge sub-stream), q = lane&15 (dim quad)
__global__ __launch_bounds__(256) void node_aggregate(
    const float4* __restrict__ feat4, const int* __restrict__ off,
    const int* __restrict__ elist,
    float4* __restrict__ aggs4, float4* __restrict__ aggm4, int nNodes) {
    int node = blockIdx.x * 4 + (threadIdx.x >> 6);
    if (node >= nNodes) return;
    int lane = threadIdx.x & 63;
    int g = lane >> 4, q = lane & 15;
    int beg = off[node], end = off[node + 1];
    float4 s = make_float4(0.f, 0.f, 0.f, 0.f);
    float4 p = make_float4(1.f, 1.f, 1.f, 1.f);
    for (int i = beg + g; i < end; i += 4) {
        float4 x = feat4[(size_t)elist[i] * 16 + q];
        s.x += x.x; s.y += x.y; s.z += x.z; s.w += x.w;
        p.x *= x.x; p.y *= x.y; p.z *= x.z; p.w *= x.w;
    }
    #pragma unroll
    for (int d = 16; d < 64; d <<= 1) {
        s.x += __shfl_xor(s.x, d); s.y += __shfl_xor(s.y, d);
        s.z += __shfl_xor(s.z, d); s.w += __shfl_xor(s.w, d);
        p.x *= __shfl_xor(p.x, d); p.y *= __shfl_xor(p.y, d);
        p.z *= __shfl_xor(p.z, d); p.w *= __shfl_xor(p.w, d);
    }
    if (g == 0) {
        aggs4[(size_t)node * 16 + q] = s;
        aggm4[(size_t)node * 16 + q] = p;
    }
}

// ---------------------------------------------------------------- W pack
// frag = (ct*KT + kt)*64 + lane; lane holds W[ct*16+(lane&15)][kt*32+(lane>>4)*8+j]
__global__ __launch_bounds__(256) void pack_weights(
    const float* __restrict__ W1, const float* __restrict__ W2,
    const float* __restrict__ W3,
    u16* __restrict__ P1h, u16* __restrict__ P1l,
    u16* __restrict__ P2h, u16* __restrict__ P2l,
    u16* __restrict__ P3h, u16* __restrict__ P3l) {
    int t = blockIdx.x * 256 + threadIdx.x;
    const float* W; u16 *Ph, *Pl; int K, frag;
    if (t < 10240)        { W = W1; Ph = P1h; Pl = P1l; K = 320; frag = t; }
    else if (t < 18432)   { W = W2; Ph = P2h; Pl = P2l; K = 256; frag = t - 10240; }
    else if (t < 20480)   { W = W3; Ph = P3h; Pl = P3l; K = 256; frag = t - 18432; }
    else return;
    int KT = K / 32;
    int lane = frag & 63;
    int tile = frag >> 6;
    int kt = tile % KT;
    int ct = tile / KT;
    int row = ct * 16 + (lane & 15);
    int k0 = kt * 32 + (lane >> 4) * 8;
    const float* src = W + (size_t)row * K + k0;
    u16* dh = Ph + (size_t)frag * 8;
    u16* dl = Pl + (size_t)frag * 8;
    #pragma unroll
    for (int j = 0; j < 8; ++j) {
        u16 h, l;
        split_bf16(src[j], h, l);
        dh[j] = h; dl[j] = l;
    }
}

// ---------------------------------------------------------------- MFMA MLP
// 512 threads = 8 waves (2 row-groups x 4 col-groups), MT=64 edges (4 m-tiles).
// A/B frag: lane&15 = row, k = (lane>>4)*8 + i. D: col = lane&15, row = (lane>>4)*4 + reg.
__global__ __launch_bounds__(512, 4) void mlp_mfma(
    const float* __restrict__ feat, const int* __restrict__ ei,
    const float* __restrict__ aggs, const float* __restrict__ aggm,
    const u16* __restrict__ P1h, const u16* __restrict__ P1l,
    const u16* __restrict__ P2h, const u16* __restrict__ P2l,
    const u16* __restrict__ P3h, const u16* __restrict__ P3l,
    const float* __restrict__ b1, const float* __restrict__ b2,
    const float* __restrict__ b3,
    float* __restrict__ out, int E) {
    __shared__ __align__(16) u16 Ah[MT * 320];   // 40 KiB, XOR-swizzled
    __shared__ __align__(16) u16 Al[MT * 320];   // 40 KiB

    const int tid = threadIdx.x;
    const int e0 = blockIdx.x * MT;

    // gather h0 = [feat | sum_u - f | sum_v - f | mul_u | mul_v] -> bf16 hi/lo
    for (int idx = tid; idx < MT * 80; idx += 512) {
        int r = idx / 80, rem = idx - r * 80;
        int sec = rem >> 4, q = rem & 15;
        int e = e0 + r; if (e >= E) e = E - 1;
        const float4* f4 = (const float4*)(feat + (size_t)e * 64);
        float4 val;
        if (sec == 0) {
            val = f4[q];
        } else if (sec == 1) {
            int u = ei[e];
            float4 s = ((const float4*)(aggs + (size_t)u * 64))[q];
            float4 f = f4[q];
            val = make_float4(s.x - f.x, s.y - f.y, s.z - f.z, s.w - f.w);
        } else if (sec == 2) {
            int v = ei[E + e];
            float4 s = ((const float4*)(aggs + (size_t)v * 64))[q];
            float4 f = f4[q];
            val = make_float4(s.x - f.x, s.y - f.y, s.z - f.z, s.w - f.w);
        } else if (sec == 3) {
            int u = ei[e];
            val = ((const float4*)(aggm + (size_t)u * 64))[q];
        } else {
            int v = ei[E + e];
            val = ((const float4*)(aggm + (size_t)v * 64))[q];
        }
        u16 h0, h1, h2, h3, l0, l1, l2, l3;
        split_bf16(val.x, h0, l0); split_bf16(val.y, h1, l1);
        split_bf16(val.z, h2, l2); split_bf16(val.w, h3, l3);
        int col = sec * 64 + q * 4;
        *(ushort4*)a_ptr(Ah, r, col) = make_ushort4(h0, h1, h2, h3);
        *(ushort4*)a_ptr(Al, r, col) = make_ushort4(l0, l1, l2, l3);
    }
    __syncthreads();

    const int lane = tid & 63;
    const int w = tid >> 6;
    const int wr = w >> 2;        // 0..1: m-tiles wr*2 + {0,1}
    const int wc = w & 3;         // 0..3: col tiles wc*4 + {0..3}
    const int lrow = lane & 15;
    const int kgrp = (lane >> 4) * 8;

    const f32x4 zf = {0.f, 0.f, 0.f, 0.f};
    f32x4 acc[2][4];

    // ================= layer 1: K=320 (KT=10), relu
    #pragma unroll
    for (int i = 0; i < 2; ++i)
        #pragma unroll
        for (int j = 0; j < 4; ++j) acc[i][j] = zf;
    for (int kt = 0; kt < 10; ++kt) {
        bf16x8 ah[2], al[2];
        #pragma unroll
        for (int i = 0; i < 2; ++i) {
            int m = (wr * 2 + i) * 16 + lrow;
            ah[i] = *(const bf16x8*)a_ptr(Ah, m, kt * 32 + kgrp);
            al[i] = *(const bf16x8*)a_ptr(Al, m, kt * 32 + kgrp);
        }
        #pragma unroll
        for (int j = 0; j < 4; ++j) {
            int ct = wc * 4 + j;
            const size_t fb = ((size_t)(ct * 10 + kt) * 64 + lane) * 8;
            bf16x8 bh = *(const bf16x8*)&P1h[fb];
            bf16x8 bl = *(const bf16x8*)&P1l[fb];
            #pragma unroll
            for (int i = 0; i < 2; ++i) {
                acc[i][j] = __builtin_amdgcn_mfma_f32_16x16x32_bf16(ah[i], bh, acc[i][j], 0, 0, 0);
                acc[i][j] = __builtin_amdgcn_mfma_f32_16x16x32_bf16(ah[i], bl, acc[i][j], 0, 0, 0);
                acc[i][j] = __builtin_amdgcn_mfma_f32_16x16x32_bf16(al[i], bh, acc[i][j], 0, 0, 0);
            }
        }
    }
    __syncthreads();
    #pragma unroll
    for (int j = 0; j < 4; ++j) {
        int n = wc * 64 + j * 16 + lrow;
        float bj = b1[n];
        #pragma unroll
        for (int i = 0; i < 2; ++i) {
            int mbase = (wr * 2 + i) * 16 + (lane >> 4) * 4;
            #pragma unroll
            for (int r = 0; r < 4; ++r) {
                float v = acc[i][j][r] + bj;
                v = v > 0.f ? v : 0.f;
                u16 h, l;
                split_bf16(v, h, l);
                *(u16*)a_ptr(Ah, mbase + r, n) = h;
                *(u16*)a_ptr(Al, mbase + r, n) = l;
            }
        }
    }
    __syncthreads();

    // ================= layer 2: K=256 (KT=8), relu
    #pragma unroll
    for (int i = 0; i < 2; ++i)
        #pragma unroll
        for (int j = 0; j < 4; ++j) acc[i][j] = zf;
    for (int kt = 0; kt < 8; ++kt) {
        bf16x8 ah[2], al[2];
        #pragma unroll
        for (int i = 0; i < 2; ++i) {
            int m = (wr * 2 + i) * 16 + lrow;
            ah[i] = *(const bf16x8*)a_ptr(Ah, m, kt * 32 + kgrp);
            al[i] = *(const bf16x8*)a_ptr(Al, m, kt * 32 + kgrp);
        }
        #pragma unroll
        for (int j = 0; j < 4; ++j) {
            int ct = wc * 4 + j;
            const size_t fb = ((size_t)(ct * 8 + kt) * 64 + lane) * 8;
            bf16x8 bh = *(const bf16x8*)&P2h[fb];
            bf16x8 bl = *(const bf16x8*)&P2l[fb];
            #pragma unroll
            for (int i = 0; i < 2; ++i) {
                acc[i][j] = __builtin_amdgcn_mfma_f32_16x16x32_bf16(ah[i], bh, acc[i][j], 0, 0, 0);
                acc[i][j] = __builtin_amdgcn_mfma_f32_16x16x32_bf16(ah[i], bl, acc[i][j], 0, 0, 0);
                acc[i][j] = __builtin_amdgcn_mfma_f32_16x16x32_bf16(al[i], bh, acc[i][j], 0, 0, 0);
            }
        }
    }
    __syncthreads();
    #pragma unroll
    for (int j = 0; j < 4; ++j) {
        int n = wc * 64 + j * 16 + lrow;
        float bj = b2[n];
        #pragma unroll
        for (int i = 0; i < 2; ++i) {
            int mbase = (wr * 2 + i) * 16 + (lane >> 4) * 4;
            #pragma unroll
            for (int r = 0; r < 4; ++r) {
                float v = acc[i][j][r] + bj;
                v = v > 0.f ? v : 0.f;
                u16 h, l;
                split_bf16(v, h, l);
                *(u16*)a_ptr(Ah, mbase + r, n) = h;
                *(u16*)a_ptr(Al, mbase + r, n) = l;
            }
        }
    }
    __syncthreads();

    // ================= layer 3: K=256 (KT=8), N=64
    // 16 (rt,ct) pairs over 8 waves: p = w*2 + q
    f32x4 acc3[2];
    acc3[0] = zf; acc3[1] = zf;
    for (int kt = 0; kt < 8; ++kt) {
        #pragma unroll
        for (int q = 0; q < 2; ++q) {
            int p = w * 2 + q;
            int rt = p >> 2, ct = p & 3;
            int m = rt * 16 + lrow;
            bf16x8 ah = *(const bf16x8*)a_ptr(Ah, m, kt * 32 + kgrp);
            bf16x8 al = *(const bf16x8*)a_ptr(Al, m, kt * 32 + kgrp);
            const size_t fb = ((size_t)(ct * 8 + kt) * 64 + lane) * 8;
            bf16x8 bh = *(const bf16x8*)&P3h[fb];
            bf16x8 bl = *(const bf16x8*)&P3l[fb];
            acc3[q] = __builtin_amdgcn_mfma_f32_16x16x32_bf16(ah, bh, acc3[q], 0, 0, 0);
            acc3[q] = __builtin_amdgcn_mfma_f32_16x16x32_bf16(ah, bl, acc3[q], 0, 0, 0);
            acc3[q] = __builtin_amdgcn_mfma_f32_16x16x32_bf16(al, bh, acc3[q], 0, 0, 0);
        }
    }
    #pragma unroll
    for (int q = 0; q < 2; ++q) {
        int p = w * 2 + q;
        int rt = p >> 2, ct = p & 3;
        int n = ct * 16 + lrow;
        float bj = b3[n];
        #pragma unroll
        for (int r = 0; r < 4; ++r) {
            int m = rt * 16 + (lane >> 4) * 4 + r;
            int e = e0 + m;
            if (e < E) out[(size_t)e * 64 + n] = acc3[q][r] + bj;
        }
    }
}

// ---------------------------------------------------------------- launcher
extern "C" void kernel_launch(void* const* d_in, const int* in_sizes, int n_in,
                              void* d_out, int out_size, void* d_ws, size_t ws_size,
                              hipStream_t stream) {
    const float* feat = (const float*)d_in[0];
    const int*   ei   = (const int*)d_in[1];
    const float* W1 = (const float*)d_in[3];
    const float* b1 = (const float*)d_in[4];
    const float* W2 = (const float*)d_in[5];
    const float* b2 = (const float*)d_in[6];
    const float* W3 = (const float*)d_in[7];
    const float* b3 = (const float*)d_in[8];
    float* out = (float*)d_out;

    const int E = in_sizes[0] / 64;
    const int N = NNODES;

    char* p = (char*)d_ws;
    float* aggs = (float*)p;            p += (size_t)N * 64 * 4;
    float* aggm = (float*)p;            p += (size_t)N * 64 * 4;
    u16* P1h = (u16*)p;                 p += 81920 * 2;
    u16* P1l = (u16*)p;                 p += 81920 * 2;
    u16* P2h = (u16*)p;                 p += 65536 * 2;
    u16* P2l = (u16*)p;                 p += 65536 * 2;
    u16* P3h = (u16*)p;                 p += 16384 * 2;
    u16* P3l = (u16*)p;                 p += 16384 * 2;
    int* deg = (int*)p;                 p += (size_t)N * 4;
    int* cursor = (int*)p;              p += (size_t)N * 4;
    int* off = (int*)p;                 p += (size_t)(N + 16) * 4;
    int* elist = (int*)p;               p += (size_t)2 * E * 4;

    hipLaunchKernelGGL(csr_init, dim3((N + 255) / 256), dim3(256), 0, stream,
                       deg, cursor, N);
    hipLaunchKernelGGL(count_deg, dim3((2 * E + 255) / 256), dim3(256), 0, stream,
                       ei, deg, 2 * E);
    hipLaunchKernelGGL(scan_deg, dim3(1), dim3(1024), 0, stream, deg, off, N);
    hipLaunchKernelGGL(fill_csr, dim3((2 * E + 255) / 256), dim3(256), 0, stream,
                       ei, off, cursor, elist, E);
    hipLaunchKernelGGL(node_aggregate, dim3((N + 3) / 4), dim3(256), 0, stream,
                       (const float4*)feat, off, elist,
                       (float4*)aggs, (float4*)aggm, N);
    hipLaunchKernelGGL(pack_weights, dim3(80), dim3(256), 0, stream,
                       W1, W2, W3, P1h, P1l, P2h, P2l, P3h, P3l);
    hipLaunchKernelGGL(mlp_mfma, dim3((E + MT - 1) / MT), dim3(512), 0, stream,
                       feat, ei, aggs, aggm,
                       P1h, P1l, P2h, P2l, P3h, P3l,
                       b1, b2, b3, out, E);
}

// Round 5
// 1201.411 us; speedup vs baseline: 15.0365x; 1.3796x over previous
//
#include <hip/hip_runtime.h>

// E = 800000, D = 64, N = 50000, MLP 320 -> 256 -> 256 -> 64.
// R4: CSR aggregation + split-bf16 MFMA MLP.
//   - operand-swapped MFMA (W = A-operand, H = B-operand): lane holds 4
//     consecutive output features of one edge -> b64 LDS epilogue writes,
//     dwordx4 final stores
//   - truncation split (hi = u>>16, lo = trunc(x - hi)), pair-packed
//   - two-stage gather prefetch (all index loads, then all float4 loads)
//   - A-tile XOR swizzle (byte ^= (row&7)<<4), MT=64, 80 KiB LDS, 2 blk/CU

#define NNODES 50000
#define MT 64

typedef unsigned short u16;
typedef unsigned int u32;
typedef __attribute__((ext_vector_type(8))) short bf16x8;
typedef __attribute__((ext_vector_type(4))) float f32x4;

// swizzled H-tile address: element (row, k) of a [64][320] u16 tile
__device__ __forceinline__ void* a_ptr(u16* base, int m, int k) {
    int byte = (m * 320 + k) * 2;
    byte ^= (m & 7) << 4;
    return (char*)base + byte;
}

__device__ inline void split_rne(float x, u16& hi, u16& lo) {   // pack path (cold)
    unsigned u = __float_as_uint(x);
    unsigned r = (u + 0x7FFFu + ((u >> 16) & 1u)) >> 16;
    hi = (u16)r;
    float hf = __uint_as_float(r << 16);
    float l = x - hf;
    unsigned ul = __float_as_uint(l);
    unsigned rl = (ul + 0x7FFFu + ((ul >> 16) & 1u)) >> 16;
    lo = (u16)rl;
}

// hot split: hi = trunc, lo = trunc(x - hi); pack two elements per u32
__device__ __forceinline__ void split_pack4(float v0, float v1, float v2, float v3,
                                            uint2& hw, uint2& lw) {
    u32 u0 = __float_as_uint(v0), u1 = __float_as_uint(v1);
    u32 u2 = __float_as_uint(v2), u3 = __float_as_uint(v3);
    hw.x = (u0 >> 16) | (u1 & 0xFFFF0000u);
    hw.y = (u2 >> 16) | (u3 & 0xFFFF0000u);
    float l0 = v0 - __uint_as_float(u0 & 0xFFFF0000u);
    float l1 = v1 - __uint_as_float(u1 & 0xFFFF0000u);
    float l2 = v2 - __uint_as_float(u2 & 0xFFFF0000u);
    float l3 = v3 - __uint_as_float(u3 & 0xFFFF0000u);
    u32 w0 = __float_as_uint(l0), w1 = __float_as_uint(l1);
    u32 w2 = __float_as_uint(l2), w3 = __float_as_uint(l3);
    lw.x = (w0 >> 16) | (w1 & 0xFFFF0000u);
    lw.y = (w2 >> 16) | (w3 & 0xFFFF0000u);
}

// ---------------------------------------------------------------- CSR build
__global__ __launch_bounds__(256) void csr_init(int* __restrict__ deg,
                                                int* __restrict__ cursor, int n) {
    int t = blockIdx.x * 256 + threadIdx.x;
    if (t < n) { deg[t] = 0; cursor[t] = 0; }
}

__global__ __launch_bounds__(256) void count_deg(const int* __restrict__ ei,
                                                 int* __restrict__ deg, int twoE) {
    int t = blockIdx.x * 256 + threadIdx.x;
    if (t < twoE) atomicAdd(&deg[ei[t]], 1);
}

__global__ __launch_bounds__(1024) void scan_deg(const int* __restrict__ deg,
                                                 int* __restrict__ off, int n) {
    __shared__ int buf[1024];
    __shared__ int carry;
    int tid = threadIdx.x;
    if (tid == 0) carry = 0;
    __syncthreads();
    for (int base = 0; base < n; base += 1024) {
        int v = (base + tid < n) ? deg[base + tid] : 0;
        buf[tid] = v;
        __syncthreads();
        int acc = v;
        for (int s = 1; s < 1024; s <<= 1) {
            int t = (tid >= s) ? buf[tid - s] : 0;
            __syncthreads();
            acc += t;
            buf[tid] = acc;
            __syncthreads();
        }
        if (base + tid < n) off[base + tid] = carry + acc - v;
        int total = buf[1023];
        __syncthreads();
        if (tid == 0) carry += total;
        __syncthreads();
    }
    if (tid == 0) off[n] = carry;
}

__global__ __launch_bounds__(256) void fill_csr(const int* __restrict__ ei,
                                                const int* __restrict__ off,
                                                int* __restrict__ cursor,
                                                int* __restrict__ elist,
                                                int E) {
    int t = blockIdx.x * 256 + threadIdx.x;
    if (t >= 2 * E) return;
    int n = ei[t];
    int p = atomicAdd(&cursor[n], 1);
    elist[off[n] + p] = (t < E) ? t : t - E;
}

// one wave per node; lanes: g = lane>>4 (edge sub-stream), q = lane&15 (dim quad)
__global__ __launch_bounds__(256) void node_aggregate(
    const float4* __restrict__ feat4, const int* __restrict__ off,
    const int* __restrict__ elist,
    float4* __restrict__ aggs4, float4* __restrict__ aggm4, int nNodes) {
    int node = blockIdx.x * 4 + (threadIdx.x >> 6);
    if (node >= nNodes) return;
    int lane = threadIdx.x & 63;
    int g = lane >> 4, q = lane & 15;
    int beg = off[node], end = off[node + 1];
    float4 s = make_float4(0.f, 0.f, 0.f, 0.f);
    float4 p = make_float4(1.f, 1.f, 1.f, 1.f);
    for (int i = beg + g; i < end; i += 4) {
        float4 x = feat4[(size_t)elist[i] * 16 + q];
        s.x += x.x; s.y += x.y; s.z += x.z; s.w += x.w;
        p.x *= x.x; p.y *= x.y; p.z *= x.z; p.w *= x.w;
    }
    #pragma unroll
    for (int d = 16; d < 64; d <<= 1) {
        s.x += __shfl_xor(s.x, d); s.y += __shfl_xor(s.y, d);
        s.z += __shfl_xor(s.z, d); s.w += __shfl_xor(s.w, d);
        p.x *= __shfl_xor(p.x, d); p.y *= __shfl_xor(p.y, d);
        p.z *= __shfl_xor(p.z, d); p.w *= __shfl_xor(p.w, d);
    }
    if (g == 0) {
        aggs4[(size_t)node * 16 + q] = s;
        aggm4[(size_t)node * 16 + q] = p;
    }
}

// ---------------------------------------------------------------- W pack
// frag = (ct*KT + kt)*64 + lane; lane holds W[ct*16+(lane&15)][kt*32+(lane>>4)*8+j]
__global__ __launch_bounds__(256) void pack_weights(
    const float* __restrict__ W1, const float* __restrict__ W2,
    const float* __restrict__ W3,
    u16* __restrict__ P1h, u16* __restrict__ P1l,
    u16* __restrict__ P2h, u16* __restrict__ P2l,
    u16* __restrict__ P3h, u16* __restrict__ P3l) {
    int t = blockIdx.x * 256 + threadIdx.x;
    const float* W; u16 *Ph, *Pl; int K, frag;
    if (t < 10240)        { W = W1; Ph = P1h; Pl = P1l; K = 320; frag = t; }
    else if (t < 18432)   { W = W2; Ph = P2h; Pl = P2l; K = 256; frag = t - 10240; }
    else if (t < 20480)   { W = W3; Ph = P3h; Pl = P3l; K = 256; frag = t - 18432; }
    else return;
    int KT = K / 32;
    int lane = frag & 63;
    int tile = frag >> 6;
    int kt = tile % KT;
    int ct = tile / KT;
    int row = ct * 16 + (lane & 15);
    int k0 = kt * 32 + (lane >> 4) * 8;
    const float* src = W + (size_t)row * K + k0;
    u16* dh = Ph + (size_t)frag * 8;
    u16* dl = Pl + (size_t)frag * 8;
    #pragma unroll
    for (int j = 0; j < 8; ++j) {
        u16 h, l;
        split_rne(src[j], h, l);
        dh[j] = h; dl[j] = l;
    }
}

// ---------------------------------------------------------------- MFMA MLP
// 512 threads = 8 waves (wr in 0..1 x wc in 0..3), MT=64 edges (4 e-tiles).
// MFMA(A = W-frag, B = H-frag): D col(lane&15) = edge, row((lane>>4)*4+reg) =
// 4 consecutive output features.
__global__ __launch_bounds__(512, 4) void mlp_mfma(
    const float* __restrict__ feat, const int* __restrict__ ei,
    const float* __restrict__ aggs, const float* __restrict__ aggm,
    const u16* __restrict__ P1h, const u16* __restrict__ P1l,
    const u16* __restrict__ P2h, const u16* __restrict__ P2l,
    const u16* __restrict__ P3h, const u16* __restrict__ P3l,
    const float* __restrict__ b1, const float* __restrict__ b2,
    const float* __restrict__ b3,
    float* __restrict__ out, int E) {
    __shared__ __align__(16) u16 Ah[MT * 320];   // 40 KiB, XOR-swizzled
    __shared__ __align__(16) u16 Al[MT * 320];   // 40 KiB

    const int tid = threadIdx.x;
    const int e0 = blockIdx.x * MT;

    // ---- gather h0 = [feat | sum_u-f | sum_v-f | mul_u | mul_v], 2-stage prefetch
    {
        int sc[10], qn[10], rr[10];
        int nodev[10];
        #pragma unroll
        for (int it = 0; it < 10; ++it) {
            int idx = tid + it * 512;            // < 5120
            int r = idx / 80, rem = idx - r * 80;
            sc[it] = rem >> 4; qn[it] = rem & 15; rr[it] = r;
            int e = e0 + r; if (e >= E) e = E - 1;
            int sec = sc[it];
            // stage 0: node-index loads (sec0 harmlessly loads ei[e])
            nodev[it] = ei[(size_t)((sec == 2 || sec == 4) ? E : 0) + e];
        }
        float4 pv[10], fv[10];
        #pragma unroll
        for (int it = 0; it < 10; ++it) {
            int sec = sc[it];
            int e = e0 + rr[it]; if (e >= E) e = E - 1;
            const float* bp;
            size_t row;
            if (sec == 0)      { bp = feat; row = (size_t)e * 64; }
            else if (sec <= 2) { bp = aggs; row = (size_t)nodev[it] * 64; }
            else               { bp = aggm; row = (size_t)nodev[it] * 64; }
            pv[it] = ((const float4*)(bp + row))[qn[it]];
            fv[it] = ((const float4*)(feat + (size_t)e * 64))[qn[it]];
        }
        #pragma unroll
        for (int it = 0; it < 10; ++it) {
            int sec = sc[it];
            float4 v = pv[it];
            if (sec == 1 || sec == 2) {
                v.x -= fv[it].x; v.y -= fv[it].y; v.z -= fv[it].z; v.w -= fv[it].w;
            }
            uint2 hw, lw;
            split_pack4(v.x, v.y, v.z, v.w, hw, lw);
            int col = sec * 64 + qn[it] * 4;
            *(uint2*)a_ptr(Ah, rr[it], col) = hw;
            *(uint2*)a_ptr(Al, rr[it], col) = lw;
        }
    }
    __syncthreads();

    const int lane = tid & 63;
    const int w = tid >> 6;
    const int wr = w >> 2;        // 0..1: e-tiles wr*2 + {0,1}
    const int wc = w & 3;         // 0..3: feature tiles wc*4 + {0..3}
    const int lrow = lane & 15;
    const int kgrp = (lane >> 4) * 8;

    const f32x4 zf = {0.f, 0.f, 0.f, 0.f};
    f32x4 acc[2][4];

    // ================= layer 1: K=320 (KT=10), relu
    #pragma unroll
    for (int i = 0; i < 2; ++i)
        #pragma unroll
        for (int j = 0; j < 4; ++j) acc[i][j] = zf;
    {
        const u16 *wbh[4], *wbl[4];
        #pragma unroll
        for (int j = 0; j < 4; ++j) {
            size_t off = ((size_t)(wc * 4 + j) * 10 * 64 + lane) * 8;
            wbh[j] = P1h + off; wbl[j] = P1l + off;
        }
        for (int kt = 0; kt < 10; ++kt) {
            bf16x8 hh[2], hl[2];
            #pragma unroll
            for (int i = 0; i < 2; ++i) {
                int er = (wr * 2 + i) * 16 + lrow;
                hh[i] = *(const bf16x8*)a_ptr(Ah, er, kt * 32 + kgrp);
                hl[i] = *(const bf16x8*)a_ptr(Al, er, kt * 32 + kgrp);
            }
            #pragma unroll
            for (int j = 0; j < 4; ++j) {
                bf16x8 wh = *(const bf16x8*)(wbh[j] + kt * 512);
                bf16x8 wl = *(const bf16x8*)(wbl[j] + kt * 512);
                #pragma unroll
                for (int i = 0; i < 2; ++i) {
                    acc[i][j] = __builtin_amdgcn_mfma_f32_16x16x32_bf16(wh, hh[i], acc[i][j], 0, 0, 0);
                    acc[i][j] = __builtin_amdgcn_mfma_f32_16x16x32_bf16(wl, hh[i], acc[i][j], 0, 0, 0);
                    acc[i][j] = __builtin_amdgcn_mfma_f32_16x16x32_bf16(wh, hl[i], acc[i][j], 0, 0, 0);
                }
            }
        }
    }
    __syncthreads();
    #pragma unroll
    for (int j = 0; j < 4; ++j) {
        int nb = (wc * 4 + j) * 16 + (lane >> 4) * 4;
        float4 bv = *(const float4*)&b1[nb];
        #pragma unroll
        for (int i = 0; i < 2; ++i) {
            int e = (wr * 2 + i) * 16 + lrow;
            float v0 = fmaxf(acc[i][j][0] + bv.x, 0.f);
            float v1 = fmaxf(acc[i][j][1] + bv.y, 0.f);
            float v2 = fmaxf(acc[i][j][2] + bv.z, 0.f);
            float v3 = fmaxf(acc[i][j][3] + bv.w, 0.f);
            uint2 hw, lw;
            split_pack4(v0, v1, v2, v3, hw, lw);
            *(uint2*)a_ptr(Ah, e, nb) = hw;
            *(uint2*)a_ptr(Al, e, nb) = lw;
        }
    }
    __syncthreads();

    // ================= layer 2: K=256 (KT=8), relu
    #pragma unroll
    for (int i = 0; i < 2; ++i)
        #pragma unroll
        for (int j = 0; j < 4; ++j) acc[i][j] = zf;
    {
        const u16 *wbh[4], *wbl[4];
        #pragma unroll
        for (int j = 0; j < 4; ++j) {
            size_t off = ((size_t)(wc * 4 + j) * 8 * 64 + lane) * 8;
            wbh[j] = P2h + off; wbl[j] = P2l + off;
        }
        for (int kt = 0; kt < 8; ++kt) {
            bf16x8 hh[2], hl[2];
            #pragma unroll
            for (int i = 0; i < 2; ++i) {
                int er = (wr * 2 + i) * 16 + lrow;
                hh[i] = *(const bf16x8*)a_ptr(Ah, er, kt * 32 + kgrp);
                hl[i] = *(const bf16x8*)a_ptr(Al, er, kt * 32 + kgrp);
            }
            #pragma unroll
            for (int j = 0; j < 4; ++j) {
                bf16x8 wh = *(const bf16x8*)(wbh[j] + kt * 512);
                bf16x8 wl = *(const bf16x8*)(wbl[j] + kt * 512);
                #pragma unroll
                for (int i = 0; i < 2; ++i) {
                    acc[i][j] = __builtin_amdgcn_mfma_f32_16x16x32_bf16(wh, hh[i], acc[i][j], 0, 0, 0);
                    acc[i][j] = __builtin_amdgcn_mfma_f32_16x16x32_bf16(wl, hh[i], acc[i][j], 0, 0, 0);
                    acc[i][j] = __builtin_amdgcn_mfma_f32_16x16x32_bf16(wh, hl[i], acc[i][j], 0, 0, 0);
                }
            }
        }
    }
    __syncthreads();
    #pragma unroll
    for (int j = 0; j < 4; ++j) {
        int nb = (wc * 4 + j) * 16 + (lane >> 4) * 4;
        float4 bv = *(const float4*)&b2[nb];
        #pragma unroll
        for (int i = 0; i < 2; ++i) {
            int e = (wr * 2 + i) * 16 + lrow;
            float v0 = fmaxf(acc[i][j][0] + bv.x, 0.f);
            float v1 = fmaxf(acc[i][j][1] + bv.y, 0.f);
            float v2 = fmaxf(acc[i][j][2] + bv.z, 0.f);
            float v3 = fmaxf(acc[i][j][3] + bv.w, 0.f);
            uint2 hw, lw;
            split_pack4(v0, v1, v2, v3, hw, lw);
            *(uint2*)a_ptr(Ah, e, nb) = hw;
            *(uint2*)a_ptr(Al, e, nb) = lw;
        }
    }
    __syncthreads();

    // ================= layer 3: K=256 (KT=8), 64 features
    // 16 (et,ct) pairs over 8 waves: p = w*2 + q
    f32x4 acc3[2];
    acc3[0] = zf; acc3[1] = zf;
    for (int kt = 0; kt < 8; ++kt) {
        #pragma unroll
        for (int q = 0; q < 2; ++q) {
            int p = w * 2 + q;
            int et = p >> 2, ct = p & 3;
            int er = et * 16 + lrow;
            bf16x8 hh = *(const bf16x8*)a_ptr(Ah, er, kt * 32 + kgrp);
            bf16x8 hl = *(const bf16x8*)a_ptr(Al, er, kt * 32 + kgrp);
            const size_t fb = ((size_t)(ct * 8 + kt) * 64 + lane) * 8;
            bf16x8 wh = *(const bf16x8*)&P3h[fb];
            bf16x8 wl = *(const bf16x8*)&P3l[fb];
            acc3[q] = __builtin_amdgcn_mfma_f32_16x16x32_bf16(wh, hh, acc3[q], 0, 0, 0);
            acc3[q] = __builtin_amdgcn_mfma_f32_16x16x32_bf16(wl, hh, acc3[q], 0, 0, 0);
            acc3[q] = __builtin_amdgcn_mfma_f32_16x16x32_bf16(wh, hl, acc3[q], 0, 0, 0);
        }
    }
    #pragma unroll
    for (int q = 0; q < 2; ++q) {
        int p = w * 2 + q;
        int et = p >> 2, ct = p & 3;
        int e = e0 + et * 16 + lrow;
        int nb = ct * 16 + (lane >> 4) * 4;
        float4 bv = *(const float4*)&b3[nb];
        float4 o;
        o.x = acc3[q][0] + bv.x; o.y = acc3[q][1] + bv.y;
        o.z = acc3[q][2] + bv.z; o.w = acc3[q][3] + bv.w;
        if (e < E) *(float4*)&out[(size_t)e * 64 + nb] = o;
    }
}

// ---------------------------------------------------------------- launcher
extern "C" void kernel_launch(void* const* d_in, const int* in_sizes, int n_in,
                              void* d_out, int out_size, void* d_ws, size_t ws_size,
                              hipStream_t stream) {
    const float* feat = (const float*)d_in[0];
    const int*   ei   = (const int*)d_in[1];
    const float* W1 = (const float*)d_in[3];
    const float* b1 = (const float*)d_in[4];
    const float* W2 = (const float*)d_in[5];
    const float* b2 = (const float*)d_in[6];
    const float* W3 = (const float*)d_in[7];
    const float* b3 = (const float*)d_in[8];
    float* out = (float*)d_out;

    const int E = in_sizes[0] / 64;
    const int N = NNODES;

    char* p = (char*)d_ws;
    float* aggs = (float*)p;            p += (size_t)N * 64 * 4;
    float* aggm = (float*)p;            p += (size_t)N * 64 * 4;
    u16* P1h = (u16*)p;                 p += 81920 * 2;
    u16* P1l = (u16*)p;                 p += 81920 * 2;
    u16* P2h = (u16*)p;                 p += 65536 * 2;
    u16* P2l = (u16*)p;                 p += 65536 * 2;
    u16* P3h = (u16*)p;                 p += 16384 * 2;
    u16* P3l = (u16*)p;                 p += 16384 * 2;
    int* deg = (int*)p;                 p += (size_t)N * 4;
    int* cursor = (int*)p;              p += (size_t)N * 4;
    int* off = (int*)p;                 p += (size_t)(N + 16) * 4;
    int* elist = (int*)p;               p += (size_t)2 * E * 4;

    hipLaunchKernelGGL(csr_init, dim3((N + 255) / 256), dim3(256), 0, stream,
                       deg, cursor, N);
    hipLaunchKernelGGL(count_deg, dim3((2 * E + 255) / 256), dim3(256), 0, stream,
                       ei, deg, 2 * E);
    hipLaunchKernelGGL(scan_deg, dim3(1), dim3(1024), 0, stream, deg, off, N);
    hipLaunchKernelGGL(fill_csr, dim3((2 * E + 255) / 256), dim3(256), 0, stream,
                       ei, off, cursor, elist, E);
    hipLaunchKernelGGL(node_aggregate, dim3((N + 3) / 4), dim3(256), 0, stream,
                       (const float4*)feat, off, elist,
                       (float4*)aggs, (float4*)aggm, N);
    hipLaunchKernelGGL(pack_weights, dim3(80), dim3(256), 0, stream,
                       W1, W2, W3, P1h, P1l, P2h, P2l, P3h, P3l);
    hipLaunchKernelGGL(mlp_mfma, dim3((E + MT - 1) / MT), dim3(512), 0, stream,
                       feat, ei, aggs, aggm,
                       P1h, P1l, P2h, P2l, P3h, P3l,
                       b1, b2, b3, out, E);
}

// Round 6
// 1183.765 us; speedup vs baseline: 15.2606x; 1.0149x over previous
//
#include <hip/hip_runtime.h>

// E = 800000, D = 64, N = 50000, MLP 320 -> 256 -> 256 -> 64.
// R5: - layer-1 linearity fold: W1' = [W1a-W1b-W1c | W1b | W1c | W1d | W1e],
//       h0 = [feat, Su, Sv, Mu, Mv] (no per-edge subtraction, no feat re-read)
//     - node aggregates pre-split ONCE per node into packed u16 hi/lo tables;
//       gather becomes load-16B -> ds_write_b128 with zero split VALU
//     - v_perm_b32 packing for remaining splits (feat section, epilogues)
//     - s_setprio around MFMA clusters; single-pass scan
//
// d_ws: sumH/sumL/mulH/mulL u16[N*64] | P1h/P1l u16[81920] | P2h/P2l u16[65536]
//       | P3h/P3l u16[16384] | deg int[N] | cursor int[N] | off int[N+16] | elist int[2E]

#define NNODES 50000
#define MT 64

typedef unsigned short u16;
typedef unsigned int u32;
typedef __attribute__((ext_vector_type(8))) short bf16x8;
typedef __attribute__((ext_vector_type(4))) float f32x4;

#define PSEL 0x07060302u   // result = [b.hi16, a.hi16] packed (a=elem0 -> low half)

// swizzled H-tile address: element (m, k) of a [64][320] u16 tile
__device__ __forceinline__ void* a_ptr(u16* base, int m, int k) {
    int byte = (m * 320 + k) * 2;
    byte ^= (m & 7) << 4;
    return (char*)base + byte;
}

__device__ inline void split_rne(float x, u16& hi, u16& lo) {   // cold pack path
    unsigned u = __float_as_uint(x);
    unsigned r = (u + 0x7FFFu + ((u >> 16) & 1u)) >> 16;
    hi = (u16)r;
    float hf = __uint_as_float(r << 16);
    float l = x - hf;
    unsigned ul = __float_as_uint(l);
    unsigned rl = (ul + 0x7FFFu + ((ul >> 16) & 1u)) >> 16;
    lo = (u16)rl;
}

// hot split: hi = trunc, lo = trunc(x - hi); perm-packed
__device__ __forceinline__ void split_pack4(float v0, float v1, float v2, float v3,
                                            uint2& hw, uint2& lw) {
    u32 u0 = __float_as_uint(v0), u1 = __float_as_uint(v1);
    u32 u2 = __float_as_uint(v2), u3 = __float_as_uint(v3);
    hw.x = __builtin_amdgcn_perm(u1, u0, PSEL);
    hw.y = __builtin_amdgcn_perm(u3, u2, PSEL);
    float l0 = v0 - __uint_as_float(u0 & 0xFFFF0000u);
    float l1 = v1 - __uint_as_float(u1 & 0xFFFF0000u);
    float l2 = v2 - __uint_as_float(u2 & 0xFFFF0000u);
    float l3 = v3 - __uint_as_float(u3 & 0xFFFF0000u);
    lw.x = __builtin_amdgcn_perm(__float_as_uint(l1), __float_as_uint(l0), PSEL);
    lw.y = __builtin_amdgcn_perm(__float_as_uint(l3), __float_as_uint(l2), PSEL);
}

// ---------------------------------------------------------------- CSR build
__global__ __launch_bounds__(256) void csr_init(int* __restrict__ deg,
                                                int* __restrict__ cursor, int n) {
    int t = blockIdx.x * 256 + threadIdx.x;
    if (t < n) { deg[t] = 0; cursor[t] = 0; }
}

__global__ __launch_bounds__(256) void count_deg(const int* __restrict__ ei,
                                                 int* __restrict__ deg, int twoE) {
    int t = blockIdx.x * 256 + threadIdx.x;
    if (t < twoE) atomicAdd(&deg[ei[t]], 1);
}

// single block, 1024 threads: chunked serial + block-scan of partials
__global__ __launch_bounds__(1024) void scan_deg(const int* __restrict__ deg,
                                                 int* __restrict__ off, int n) {
    __shared__ int part[1024];
    int tid = threadIdx.x;
    int chunk = (n + 1023) / 1024;
    int lo = tid * chunk;
    int hi = lo + chunk; if (hi > n) hi = n;
    int s = 0;
    for (int i = lo; i < hi; ++i) s += deg[i];
    part[tid] = s;
    __syncthreads();
    for (int st = 1; st < 1024; st <<= 1) {
        int v = (tid >= st) ? part[tid - st] : 0;
        __syncthreads();
        part[tid] += v;
        __syncthreads();
    }
    int pre = tid ? part[tid - 1] : 0;
    for (int i = lo; i < hi; ++i) { off[i] = pre; pre += deg[i]; }
    if (tid == 1023) off[n] = pre;
}

__global__ __launch_bounds__(256) void fill_csr(const int* __restrict__ ei,
                                                const int* __restrict__ off,
                                                int* __restrict__ cursor,
                                                int* __restrict__ elist,
                                                int E) {
    int t = blockIdx.x * 256 + threadIdx.x;
    if (t >= 2 * E) return;
    int n = ei[t];
    int p = atomicAdd(&cursor[n], 1);
    elist[off[n] + p] = (t < E) ? t : t - E;
}

// one wave per node; writes packed split hi/lo u16 tables directly
__global__ __launch_bounds__(256) void node_aggregate(
    const float4* __restrict__ feat4, const int* __restrict__ off,
    const int* __restrict__ elist,
    u16* __restrict__ sumH, u16* __restrict__ sumL,
    u16* __restrict__ mulH, u16* __restrict__ mulL, int nNodes) {
    int node = blockIdx.x * 4 + (threadIdx.x >> 6);
    if (node >= nNodes) return;
    int lane = threadIdx.x & 63;
    int g = lane >> 4, q = lane & 15;
    int beg = off[node], end = off[node + 1];
    float4 s = make_float4(0.f, 0.f, 0.f, 0.f);
    float4 p = make_float4(1.f, 1.f, 1.f, 1.f);
    for (int i = beg + g; i < end; i += 4) {
        float4 x = feat4[(size_t)elist[i] * 16 + q];
        s.x += x.x; s.y += x.y; s.z += x.z; s.w += x.w;
        p.x *= x.x; p.y *= x.y; p.z *= x.z; p.w *= x.w;
    }
    #pragma unroll
    for (int d = 16; d < 64; d <<= 1) {
        s.x += __shfl_xor(s.x, d); s.y += __shfl_xor(s.y, d);
        s.z += __shfl_xor(s.z, d); s.w += __shfl_xor(s.w, d);
        p.x *= __shfl_xor(p.x, d); p.y *= __shfl_xor(p.y, d);
        p.z *= __shfl_xor(p.z, d); p.w *= __shfl_xor(p.w, d);
    }
    if (g == 0) {
        uint2 hw, lw;
        size_t base = (size_t)node * 64 + q * 4;
        split_pack4(s.x, s.y, s.z, s.w, hw, lw);
        *(uint2*)&sumH[base] = hw;
        *(uint2*)&sumL[base] = lw;
        split_pack4(p.x, p.y, p.z, p.w, hw, lw);
        *(uint2*)&mulH[base] = hw;
        *(uint2*)&mulL[base] = lw;
    }
}

// ---------------------------------------------------------------- W pack
// frag = (ct*KT + kt)*64 + lane; lane holds W[ct*16+(lane&15)][kt*32+(lane>>4)*8+j]
// Layer-1 fold: col k<64 -> W1[r][k] - W1[r][64+k] - W1[r][128+k]
__global__ __launch_bounds__(256) void pack_weights(
    const float* __restrict__ W1, const float* __restrict__ W2,
    const float* __restrict__ W3,
    u16* __restrict__ P1h, u16* __restrict__ P1l,
    u16* __restrict__ P2h, u16* __restrict__ P2l,
    u16* __restrict__ P3h, u16* __restrict__ P3l) {
    int t = blockIdx.x * 256 + threadIdx.x;
    const float* W; u16 *Ph, *Pl; int K, frag, fold = 0;
    if (t < 10240)        { W = W1; Ph = P1h; Pl = P1l; K = 320; frag = t; fold = 1; }
    else if (t < 18432)   { W = W2; Ph = P2h; Pl = P2l; K = 256; frag = t - 10240; }
    else if (t < 20480)   { W = W3; Ph = P3h; Pl = P3l; K = 256; frag = t - 18432; }
    else return;
    int KT = K / 32;
    int lane = frag & 63;
    int tile = frag >> 6;
    int kt = tile % KT;
    int ct = tile / KT;
    int row = ct * 16 + (lane & 15);
    int k0 = kt * 32 + (lane >> 4) * 8;
    const float* src = W + (size_t)row * K;
    u16* dh = Ph + (size_t)frag * 8;
    u16* dl = Pl + (size_t)frag * 8;
    #pragma unroll
    for (int j = 0; j < 8; ++j) {
        int k = k0 + j;
        float v = src[k];
        if (fold && k < 64) v -= src[64 + k] + src[128 + k];
        u16 h, l;
        split_rne(v, h, l);
        dh[j] = h; dl[j] = l;
    }
}

// ---------------------------------------------------------------- MFMA MLP
// 512 threads = 8 waves (wr 0..1 x wc 0..3), MT=64 edges.
// MFMA(A = W-frag, B = H-frag): D col(lane&15) = edge, row = 4 consecutive features.
__global__ __launch_bounds__(512, 4) void mlp_mfma(
    const float* __restrict__ feat, const int* __restrict__ ei,
    const u16* __restrict__ sumH, const u16* __restrict__ sumL,
    const u16* __restrict__ mulH, const u16* __restrict__ mulL,
    const u16* __restrict__ P1h, const u16* __restrict__ P1l,
    const u16* __restrict__ P2h, const u16* __restrict__ P2l,
    const u16* __restrict__ P3h, const u16* __restrict__ P3l,
    const float* __restrict__ b1, const float* __restrict__ b2,
    const float* __restrict__ b3,
    float* __restrict__ out, int E) {
    __shared__ __align__(16) u16 Ah[MT * 320];   // 40 KiB, XOR-swizzled
    __shared__ __align__(16) u16 Al[MT * 320];   // 40 KiB

    const int tid = threadIdx.x;
    const int e0 = blockIdx.x * MT;

    // ---- gather h0 = [feat | Su | Sv | Mu | Mv]
    // 2560 items = 64 edges x 5 sections x 8 octs(8 elems each); 5 items/thread
    #pragma unroll
    for (int it = 0; it < 5; ++it) {
        int idx = tid + it * 512;
        int r = idx / 40;
        int rem = idx - r * 40;
        int sec = rem >> 3, oct = rem & 7;
        int e = e0 + r; if (e >= E) e = E - 1;
        int col = sec * 64 + oct * 8;
        uint4 hv, lv;
        if (sec == 0) {
            const float4* f4 = (const float4*)(feat + (size_t)e * 64 + oct * 8);
            float4 a = f4[0], b = f4[1];
            u32 u0 = __float_as_uint(a.x), u1 = __float_as_uint(a.y);
            u32 u2 = __float_as_uint(a.z), u3 = __float_as_uint(a.w);
            u32 u4 = __float_as_uint(b.x), u5 = __float_as_uint(b.y);
            u32 u6 = __float_as_uint(b.z), u7 = __float_as_uint(b.w);
            hv.x = __builtin_amdgcn_perm(u1, u0, PSEL);
            hv.y = __builtin_amdgcn_perm(u3, u2, PSEL);
            hv.z = __builtin_amdgcn_perm(u5, u4, PSEL);
            hv.w = __builtin_amdgcn_perm(u7, u6, PSEL);
            float l0 = a.x - __uint_as_float(u0 & 0xFFFF0000u);
            float l1 = a.y - __uint_as_float(u1 & 0xFFFF0000u);
            float l2 = a.z - __uint_as_float(u2 & 0xFFFF0000u);
            float l3 = a.w - __uint_as_float(u3 & 0xFFFF0000u);
            float l4 = b.x - __uint_as_float(u4 & 0xFFFF0000u);
            float l5 = b.y - __uint_as_float(u5 & 0xFFFF0000u);
            float l6 = b.z - __uint_as_float(u6 & 0xFFFF0000u);
            float l7 = b.w - __uint_as_float(u7 & 0xFFFF0000u);
            lv.x = __builtin_amdgcn_perm(__float_as_uint(l1), __float_as_uint(l0), PSEL);
            lv.y = __builtin_amdgcn_perm(__float_as_uint(l3), __float_as_uint(l2), PSEL);
            lv.z = __builtin_amdgcn_perm(__float_as_uint(l5), __float_as_uint(l4), PSEL);
            lv.w = __builtin_amdgcn_perm(__float_as_uint(l7), __float_as_uint(l6), PSEL);
        } else {
            int node = ei[(size_t)((sec & 1) ? 0 : E) + e];   // sec 1,3 -> u; 2,4 -> v
            const u16* Ht = (sec <= 2) ? sumH : mulH;
            const u16* Lt = (sec <= 2) ? sumL : mulL;
            size_t base = (size_t)node * 64 + oct * 8;
            hv = *(const uint4*)(Ht + base);
            lv = *(const uint4*)(Lt + base);
        }
        *(uint4*)a_ptr(Ah, r, col) = hv;
        *(uint4*)a_ptr(Al, r, col) = lv;
    }
    __syncthreads();

    const int lane = tid & 63;
    const int w = tid >> 6;
    const int wr = w >> 2;
    const int wc = w & 3;
    const int lrow = lane & 15;
    const int kgrp = (lane >> 4) * 8;

    const f32x4 zf = {0.f, 0.f, 0.f, 0.f};
    f32x4 acc[2][4];

    // ================= layer 1: K=320 (KT=10), relu
    #pragma unroll
    for (int i = 0; i < 2; ++i)
        #pragma unroll
        for (int j = 0; j < 4; ++j) acc[i][j] = zf;
    {
        const u16 *wbh[4], *wbl[4];
        #pragma unroll
        for (int j = 0; j < 4; ++j) {
            size_t off = ((size_t)(wc * 4 + j) * 10 * 64 + lane) * 8;
            wbh[j] = P1h + off; wbl[j] = P1l + off;
        }
        for (int kt = 0; kt < 10; ++kt) {
            bf16x8 hh[2], hl[2];
            #pragma unroll
            for (int i = 0; i < 2; ++i) {
                int er = (wr * 2 + i) * 16 + lrow;
                hh[i] = *(const bf16x8*)a_ptr(Ah, er, kt * 32 + kgrp);
                hl[i] = *(const bf16x8*)a_ptr(Al, er, kt * 32 + kgrp);
            }
            bf16x8 wh[4], wl[4];
            #pragma unroll
            for (int j = 0; j < 4; ++j) {
                wh[j] = *(const bf16x8*)(wbh[j] + kt * 512);
                wl[j] = *(const bf16x8*)(wbl[j] + kt * 512);
            }
            __builtin_amdgcn_s_setprio(1);
            #pragma unroll
            for (int j = 0; j < 4; ++j)
                #pragma unroll
                for (int i = 0; i < 2; ++i) {
                    acc[i][j] = __builtin_amdgcn_mfma_f32_16x16x32_bf16(wh[j], hh[i], acc[i][j], 0, 0, 0);
                    acc[i][j] = __builtin_amdgcn_mfma_f32_16x16x32_bf16(wl[j], hh[i], acc[i][j], 0, 0, 0);
                    acc[i][j] = __builtin_amdgcn_mfma_f32_16x16x32_bf16(wh[j], hl[i], acc[i][j], 0, 0, 0);
                }
            __builtin_amdgcn_s_setprio(0);
        }
    }
    __syncthreads();
    #pragma unroll
    for (int j = 0; j < 4; ++j) {
        int nb = (wc * 4 + j) * 16 + (lane >> 4) * 4;
        float4 bv = *(const float4*)&b1[nb];
        #pragma unroll
        for (int i = 0; i < 2; ++i) {
            int e = (wr * 2 + i) * 16 + lrow;
            float v0 = fmaxf(acc[i][j][0] + bv.x, 0.f);
            float v1 = fmaxf(acc[i][j][1] + bv.y, 0.f);
            float v2 = fmaxf(acc[i][j][2] + bv.z, 0.f);
            float v3 = fmaxf(acc[i][j][3] + bv.w, 0.f);
            uint2 hw, lw;
            split_pack4(v0, v1, v2, v3, hw, lw);
            *(uint2*)a_ptr(Ah, e, nb) = hw;
            *(uint2*)a_ptr(Al, e, nb) = lw;
        }
    }
    __syncthreads();

    // ================= layer 2: K=256 (KT=8), relu
    #pragma unroll
    for (int i = 0; i < 2; ++i)
        #pragma unroll
        for (int j = 0; j < 4; ++j) acc[i][j] = zf;
    {
        const u16 *wbh[4], *wbl[4];
        #pragma unroll
        for (int j = 0; j < 4; ++j) {
            size_t off = ((size_t)(wc * 4 + j) * 8 * 64 + lane) * 8;
            wbh[j] = P2h + off; wbl[j] = P2l + off;
        }
        for (int kt = 0; kt < 8; ++kt) {
            bf16x8 hh[2], hl[2];
            #pragma unroll
            for (int i = 0; i < 2; ++i) {
                int er = (wr * 2 + i) * 16 + lrow;
                hh[i] = *(const bf16x8*)a_ptr(Ah, er, kt * 32 + kgrp);
                hl[i] = *(const bf16x8*)a_ptr(Al, er, kt * 32 + kgrp);
            }
            bf16x8 wh[4], wl[4];
            #pragma unroll
            for (int j = 0; j < 4; ++j) {
                wh[j] = *(const bf16x8*)(wbh[j] + kt * 512);
                wl[j] = *(const bf16x8*)(wbl[j] + kt * 512);
            }
            __builtin_amdgcn_s_setprio(1);
            #pragma unroll
            for (int j = 0; j < 4; ++j)
                #pragma unroll
                for (int i = 0; i < 2; ++i) {
                    acc[i][j] = __builtin_amdgcn_mfma_f32_16x16x32_bf16(wh[j], hh[i], acc[i][j], 0, 0, 0);
                    acc[i][j] = __builtin_amdgcn_mfma_f32_16x16x32_bf16(wl[j], hh[i], acc[i][j], 0, 0, 0);
                    acc[i][j] = __builtin_amdgcn_mfma_f32_16x16x32_bf16(wh[j], hl[i], acc[i][j], 0, 0, 0);
                }
            __builtin_amdgcn_s_setprio(0);
        }
    }
    __syncthreads();
    #pragma unroll
    for (int j = 0; j < 4; ++j) {
        int nb = (wc * 4 + j) * 16 + (lane >> 4) * 4;
        float4 bv = *(const float4*)&b2[nb];
        #pragma unroll
        for (int i = 0; i < 2; ++i) {
            int e = (wr * 2 + i) * 16 + lrow;
            float v0 = fmaxf(acc[i][j][0] + bv.x, 0.f);
            float v1 = fmaxf(acc[i][j][1] + bv.y, 0.f);
            float v2 = fmaxf(acc[i][j][2] + bv.z, 0.f);
            float v3 = fmaxf(acc[i][j][3] + bv.w, 0.f);
            uint2 hw, lw;
            split_pack4(v0, v1, v2, v3, hw, lw);
            *(uint2*)a_ptr(Ah, e, nb) = hw;
            *(uint2*)a_ptr(Al, e, nb) = lw;
        }
    }
    __syncthreads();

    // ================= layer 3: K=256 (KT=8), 64 features
    f32x4 acc3[2];
    acc3[0] = zf; acc3[1] = zf;
    for (int kt = 0; kt < 8; ++kt) {
        __builtin_amdgcn_s_setprio(1);
        #pragma unroll
        for (int q = 0; q < 2; ++q) {
            int p = w * 2 + q;
            int et = p >> 2, ct = p & 3;
            int er = et * 16 + lrow;
            bf16x8 hh = *(const bf16x8*)a_ptr(Ah, er, kt * 32 + kgrp);
            bf16x8 hl = *(const bf16x8*)a_ptr(Al, er, kt * 32 + kgrp);
            const size_t fb = ((size_t)(ct * 8 + kt) * 64 + lane) * 8;
            bf16x8 wh = *(const bf16x8*)&P3h[fb];
            bf16x8 wl = *(const bf16x8*)&P3l[fb];
            acc3[q] = __builtin_amdgcn_mfma_f32_16x16x32_bf16(wh, hh, acc3[q], 0, 0, 0);
            acc3[q] = __builtin_amdgcn_mfma_f32_16x16x32_bf16(wl, hh, acc3[q], 0, 0, 0);
            acc3[q] = __builtin_amdgcn_mfma_f32_16x16x32_bf16(wh, hl, acc3[q], 0, 0, 0);
        }
        __builtin_amdgcn_s_setprio(0);
    }
    #pragma unroll
    for (int q = 0; q < 2; ++q) {
        int p = w * 2 + q;
        int et = p >> 2, ct = p & 3;
        int e = e0 + et * 16 + lrow;
        int nb = ct * 16 + (lane >> 4) * 4;
        float4 bv = *(const float4*)&b3[nb];
        float4 o;
        o.x = acc3[q][0] + bv.x; o.y = acc3[q][1] + bv.y;
        o.z = acc3[q][2] + bv.z; o.w = acc3[q][3] + bv.w;
        if (e < E) *(float4*)&out[(size_t)e * 64 + nb] = o;
    }
}

// ---------------------------------------------------------------- launcher
extern "C" void kernel_launch(void* const* d_in, const int* in_sizes, int n_in,
                              void* d_out, int out_size, void* d_ws, size_t ws_size,
                              hipStream_t stream) {
    const float* feat = (const float*)d_in[0];
    const int*   ei   = (const int*)d_in[1];
    const float* W1 = (const float*)d_in[3];
    const float* b1 = (const float*)d_in[4];
    const float* W2 = (const float*)d_in[5];
    const float* b2 = (const float*)d_in[6];
    const float* W3 = (const float*)d_in[7];
    const float* b3 = (const float*)d_in[8];
    float* out = (float*)d_out;

    const int E = in_sizes[0] / 64;
    const int N = NNODES;

    char* p = (char*)d_ws;
    u16* sumH = (u16*)p;                p += (size_t)N * 64 * 2;
    u16* sumL = (u16*)p;                p += (size_t)N * 64 * 2;
    u16* mulH = (u16*)p;                p += (size_t)N * 64 * 2;
    u16* mulL = (u16*)p;                p += (size_t)N * 64 * 2;
    u16* P1h = (u16*)p;                 p += 81920 * 2;
    u16* P1l = (u16*)p;                 p += 81920 * 2;
    u16* P2h = (u16*)p;                 p += 65536 * 2;
    u16* P2l = (u16*)p;                 p += 65536 * 2;
    u16* P3h = (u16*)p;                 p += 16384 * 2;
    u16* P3l = (u16*)p;                 p += 16384 * 2;
    int* deg = (int*)p;                 p += (size_t)N * 4;
    int* cursor = (int*)p;              p += (size_t)N * 4;
    int* off = (int*)p;                 p += (size_t)(N + 16) * 4;
    int* elist = (int*)p;               p += (size_t)2 * E * 4;

    hipLaunchKernelGGL(csr_init, dim3((N + 255) / 256), dim3(256), 0, stream,
                       deg, cursor, N);
    hipLaunchKernelGGL(count_deg, dim3((2 * E + 255) / 256), dim3(256), 0, stream,
                       ei, deg, 2 * E);
    hipLaunchKernelGGL(scan_deg, dim3(1), dim3(1024), 0, stream, deg, off, N);
    hipLaunchKernelGGL(fill_csr, dim3((2 * E + 255) / 256), dim3(256), 0, stream,
                       ei, off, cursor, elist, E);
    hipLaunchKernelGGL(node_aggregate, dim3((N + 3) / 4), dim3(256), 0, stream,
                       (const float4*)feat, off, elist,
                       sumH, sumL, mulH, mulL, N);
    hipLaunchKernelGGL(pack_weights, dim3(80), dim3(256), 0, stream,
                       W1, W2, W3, P1h, P1l, P2h, P2l, P3h, P3l);
    hipLaunchKernelGGL(mlp_mfma, dim3((E + MT - 1) / MT), dim3(512), 0, stream,
                       feat, ei, sumH, sumL, mulH, mulL,
                       P1h, P1l, P2h, P2l, P3h, P3l,
                       b1, b2, b3, out, E);
}